// Round 11
// baseline (4714.334 us; speedup 1.0000x reference)
//
#include <hip/hip_runtime.h>

#define BB   8
#define HH   128
#define WW   200
#define HWSZ 25600
#define C48  48
#define C64  64
#define NGRP 8
#define EPSV 1e-5f
#define LAMV 1e-4
#define SLOT 9830400          // BB*C48*HWSZ elements (one z/F/G slot)
#define DPB  1228800          // C48*HWSZ per-batch flat dim
#define Y64SZ 13107200        // BB*C64*HWSZ
#define BIGELEMS 131072000ull // 12*SLOT + Y64SZ

typedef unsigned short bf16_t;
typedef __attribute__((ext_vector_type(4))) short s4v;
typedef __attribute__((ext_vector_type(8))) short s8v;
typedef __attribute__((ext_vector_type(16))) float f32x16;

__device__ inline float b2f(bf16_t b) { return __uint_as_float(((unsigned)b) << 16); }
__device__ inline bf16_t f2b(float f) {
    unsigned u = __float_as_uint(f);
    unsigned r = u + 0x7fffu + ((u >> 16) & 1u);
    return (bf16_t)(r >> 16);
}
__device__ inline float lo16(unsigned u) { return __uint_as_float(u << 16); }
__device__ inline float hi16(unsigned u) { return __uint_as_float(u & 0xffff0000u); }
__device__ inline unsigned pack2(float lo, float hi) {
    return ((unsigned)f2b(lo)) | (((unsigned)f2b(hi)) << 16);
}
__device__ inline float4 ld4(const bf16_t* p) {
    ushort4 u = *(const ushort4*)p;
    return make_float4(b2f(u.x), b2f(u.y), b2f(u.z), b2f(u.w));
}
__device__ inline void st4(bf16_t* p, float4 v) {
    ushort4 u; u.x = f2b(v.x); u.y = f2b(v.y); u.z = f2b(v.z); u.w = f2b(v.w);
    *(ushort4*)p = u;
}
// 8 bf16 <-> 8 floats via one 16B op
__device__ inline void ld8(const bf16_t* p, float* v) {
    uint4 u = *(const uint4*)p;
    v[0] = lo16(u.x); v[1] = hi16(u.x); v[2] = lo16(u.y); v[3] = hi16(u.y);
    v[4] = lo16(u.z); v[5] = hi16(u.z); v[6] = lo16(u.w); v[7] = hi16(u.w);
}
__device__ inline void st8(bf16_t* p, const float* v) {
    uint4 u;
    u.x = pack2(v[0], v[1]); u.y = pack2(v[2], v[3]);
    u.z = pack2(v[4], v[5]); u.w = pack2(v[6], v[7]);
    *(uint4*)p = u;
}

// (mean, invstd) from f64 sums at use site
__device__ inline void ms_from(const double* __restrict__ ds, int pair, double invcnt,
                               float& mean, float& inv) {
    double s = ds[2 * pair], q = ds[2 * pair + 1];
    double m = s * invcnt;
    double v = q * invcnt - m * m;
    mean = (float)m;
    inv = (float)(1.0 / sqrt(v + (double)EPSV));
}

// ---------------- utility ----------------

__global__ void zero_kernel(float* __restrict__ p, int n) {
    int i = blockIdx.x * 256 + threadIdx.x;
    if (i < n) p[i] = 0.f;
}
__global__ void fill16_kernel(float4* __restrict__ p) {
    float4 z; z.x = z.y = z.z = z.w = 0.f;
    p[(size_t)blockIdx.x * 256 + threadIdx.x] = z;
}

// ---------------- weight packing: [kc][tap][mt][lane][8] bf16 ----------------
__global__ void pack_kernel(const float* __restrict__ w, bf16_t* __restrict__ apk,
                            int CIN, int CO_real, int total) {
    int idx = blockIdx.x * 256 + threadIdx.x;
    if (idx >= total) return;
    int j   = idx & 7;
    int l   = (idx >> 3) & 63;
    int mt  = (idx >> 9) & 1;
    int tap = (idx >> 10) % 9;
    int kc  = idx / 9216;
    int co = mt * 32 + (l & 31);
    int ci = kc * 16 + (l >> 5) * 8 + j;
    float v = (co < CO_real) ? w[((size_t)co * CIN + ci) * 9 + tap] : 0.f;
    apk[idx] = f2b(v);
}

// ---------------- conv0 (1->48) + fused BN stats ----------------
// R11: R10's x-split REVERTED (Occ 27->52% but dur 67->98µs; dur == hbm_bytes/BW, so
// conv0 is HBM-traffic-bound at ~1.2TB/s — the lever is BYTES). This round: raw output
// stored as BF16 (39.3 -> 19.7 MB writes; bn_apply reads halve too). Stats still f32
// register-accurate pre-rounding; only the value bn_apply scales gains one bf16 round,
// which the pipeline applies right after anyway.
__global__ __launch_bounds__(256) void conv0_kernel(
    const float* __restrict__ x, const float* __restrict__ w0,
    const float* __restrict__ b0, bf16_t* __restrict__ out,
    double* __restrict__ bnbin)
{
    __shared__ float xs[3 * 202];
    __shared__ float wt[480];
    __shared__ float ss[48], qq[48];
    const int tid = threadIdx.x;
    const int bI = blockIdx.x / HH, y = blockIdx.x % HH;
    for (int i = tid; i < 606; i += 256) {
        int r = i / 202, cc = i % 202;
        int gy = y + r - 1, gx = cc - 1;
        float v = 0.f;
        if ((unsigned)gy < (unsigned)HH && (unsigned)gx < (unsigned)WW)
            v = x[(size_t)bI * HWSZ + gy * WW + gx];
        xs[r * 202 + cc] = v;
    }
    for (int i = tid; i < 480; i += 256) wt[i] = (i < 432) ? w0[i] : b0[i - 432];
    if (tid < 48) { ss[tid] = 0.f; qq[tid] = 0.f; }
    __syncthreads();
    const size_t obase = (((size_t)bI * HH + y) * WW) * 48;
    float4 sacc[3], qacc[3];
    #pragma unroll
    for (int j = 0; j < 3; j++) {
        sacc[j] = make_float4(0.f, 0.f, 0.f, 0.f);
        qacc[j] = make_float4(0.f, 0.f, 0.f, 0.f);
    }
    int k3 = 0;
    for (int ch = tid; ch < 2400; ch += 256) {
        int px = (ch * 4) / 48, c0 = (ch * 4) % 48;
        float xv[3][3];
        #pragma unroll
        for (int r = 0; r < 3; r++)
            #pragma unroll
            for (int dx = 0; dx < 3; dx++)
                xv[r][dx] = xs[r * 202 + px + dx];
        float4 o;
        #pragma unroll
        for (int j = 0; j < 4; j++) {
            int c = c0 + j;
            float acc = wt[432 + c];
            #pragma unroll
            for (int r = 0; r < 3; r++)
                #pragma unroll
                for (int dx = 0; dx < 3; dx++)
                    acc = fmaf(xv[r][dx], wt[c * 9 + r * 3 + dx], acc);
            ((float*)&o)[j] = acc;
        }
        st4(out + obase + ch * 4, o);   // bf16 raw store (8B)
        sacc[k3].x += o.x; sacc[k3].y += o.y; sacc[k3].z += o.z; sacc[k3].w += o.w;
        qacc[k3].x = fmaf(o.x, o.x, qacc[k3].x);
        qacc[k3].y = fmaf(o.y, o.y, qacc[k3].y);
        qacc[k3].z = fmaf(o.z, o.z, qacc[k3].z);
        qacc[k3].w = fmaf(o.w, o.w, qacc[k3].w);
        k3 = (k3 == 2) ? 0 : k3 + 1;
    }
    #pragma unroll
    for (int j = 0; j < 3; j++) {
        int quad = (tid + 4 * j) % 12;
        atomicAdd(&ss[quad * 4 + 0], sacc[j].x);
        atomicAdd(&ss[quad * 4 + 1], sacc[j].y);
        atomicAdd(&ss[quad * 4 + 2], sacc[j].z);
        atomicAdd(&ss[quad * 4 + 3], sacc[j].w);
        atomicAdd(&qq[quad * 4 + 0], qacc[j].x);
        atomicAdd(&qq[quad * 4 + 1], qacc[j].y);
        atomicAdd(&qq[quad * 4 + 2], qacc[j].z);
        atomicAdd(&qq[quad * 4 + 3], qacc[j].w);
    }
    __syncthreads();
    if (tid < 48) {
        int bin = blockIdx.x & 7;
        unsafeAtomicAdd(&bnbin[bin * 96 + tid * 2],     (double)ss[tid]);
        unsafeAtomicAdd(&bnbin[bin * 96 + tid * 2 + 1], (double)qq[tid]);
    }
}

// 1-block: dstats[0..95] = sum of 8 bins
__global__ void bn_reduce_kernel(const double* __restrict__ bnbin, double* __restrict__ dst) {
    int t = threadIdx.x;
    if (t < 96) {
        double s = 0.0;
        #pragma unroll
        for (int j = 0; j < 8; j++) s += bnbin[j * 96 + t];
        dst[t] = s;
    }
}

// ---------------- BN apply: bf16 raw -> bf16 NHWC h ----------------
__global__ __launch_bounds__(256) void bn_apply_kernel(
    const bf16_t* __restrict__ src, bf16_t* __restrict__ dst,
    const float* __restrict__ gamma, const float* __restrict__ beta,
    const double* __restrict__ ds)
{
    __shared__ float gaT[48], beT[48];
    int tid = threadIdx.x;
    if (tid < 48) {
        float mean, inv; ms_from(ds, tid, 1.0 / 204800.0, mean, inv);
        float ga = gamma[tid] * inv;
        gaT[tid] = ga; beT[tid] = beta[tid] - mean * ga;
    }
    __syncthreads();
    size_t base = (size_t)blockIdx.x * 2048 + (size_t)tid * 8;
    int c0 = (int)(base % 48);
    float v[8];
    ld8(src + base, v);
    float r[8];
    #pragma unroll
    for (int e = 0; e < 8; e++) {
        int c = c0 + e;
        r[e] = fmaf(v[e], gaT[c], beT[c]);
    }
    st8(dst + base, r);
}

// ---------------- MFMA implicit-GEMM 3x3 conv (R5/R9 proven: weight-LDS + batched stage) ----
template<int CIN, int CIPAD, int CO, int OTS, int CG, bool RELU, bool ADDH, bool FOLDGN>
__global__ __launch_bounds__(512, 4) void conv_mfma_kernel(
    const bf16_t* __restrict__ in, const s8v* __restrict__ apk,
    const bf16_t* __restrict__ hadd, bf16_t* __restrict__ out,
    double* __restrict__ dsOut,
    const double* __restrict__ dsPrev, const float* __restrict__ gPrev,
    const float* __restrict__ bPrev)
{
    constexpr int KC  = CIN / 16;
    constexpr int NC8 = CIN / 8;
    constexpr int NITEMS = 10 * 34 * NC8;
    constexpr int NIT = (NITEMS + 511) / 512;
    const int tid  = threadIdx.x;
    const int lane = tid & 63;
    const int wv   = tid >> 6;          // 0..7 = output row within block
    const int x0 = blockIdx.x * 32;
    const int y0 = blockIdx.y * 8;
    const int b  = blockIdx.z;

    __shared__ __align__(16) bf16_t bt[10 * 34 * CIPAD];  // reused as ot[256][OTS]
    __shared__ __align__(16) s8v ws[1152];                // one kc-slice of apk (18.4KB)
    __shared__ __align__(16) float gaT[FOLDGN ? CIN : 4];
    __shared__ __align__(16) float beT[FOLDGN ? CIN : 4];
    __shared__ float ss[512], qq[512];

    if (FOLDGN) {
        if (tid < CIN) {
            float mean, inv;
            ms_from(dsPrev, b * NGRP + tid / (CIN / NGRP), 1.0 / 204800.0, mean, inv);
            float ga = gPrev[tid] * inv;
            gaT[tid] = ga; beT[tid] = bPrev[tid] - mean * ga;
        }
        __syncthreads();
    }

    // ---- input staging, batched: issue all loads, single wait, then fold+write ----
    s8v vreg[NIT];
    #pragma unroll
    for (int k = 0; k < NIT; k++) {
        int i = tid + k * 512;
        s8v t;
        #pragma unroll
        for (int e = 0; e < 8; e++) t[e] = 0;
        if (i < NITEMS) {
            int ch8 = i % NC8, p = i / NC8;
            int r = p / 34, c = p - r * 34;
            int gy = y0 + r - 1, gx = x0 + c - 1;
            if ((unsigned)gy < (unsigned)HH && (unsigned)gx < (unsigned)WW)
                t = *(const s8v*)(in + ((((size_t)b * HH + gy) * WW + gx) * CIN + ch8 * 8));
        }
        vreg[k] = t;
    }
    #pragma unroll
    for (int k = 0; k < NIT; k++) {
        int i = tid + k * 512;
        if (i >= NITEMS) continue;
        int ch8 = i % NC8, p = i / NC8;
        s8v v = vreg[k];
        if (FOLDGN) {
            int r = p / 34, c = p - r * 34;
            int gy = y0 + r - 1, gx = x0 + c - 1;
            if ((unsigned)gy < (unsigned)HH && (unsigned)gx < (unsigned)WW) {
                const float* ga8 = &gaT[ch8 * 8];
                const float* be8 = &beT[ch8 * 8];
                float f[8];
                #pragma unroll
                for (int e = 0; e < 8; e++)
                    f[e] = fmaf(b2f((bf16_t)(unsigned short)v[e]), ga8[e], be8[e]);
                unsigned p01, p23, p45, p67;
                asm("v_cvt_pk_bf16_f32 %0, %1, %2" : "=v"(p01) : "v"(f[0]), "v"(f[1]));
                asm("v_cvt_pk_bf16_f32 %0, %1, %2" : "=v"(p23) : "v"(f[2]), "v"(f[3]));
                asm("v_cvt_pk_bf16_f32 %0, %1, %2" : "=v"(p45) : "v"(f[4]), "v"(f[5]));
                asm("v_cvt_pk_bf16_f32 %0, %1, %2" : "=v"(p67) : "v"(f[6]), "v"(f[7]));
                unsigned* vp = (unsigned*)&v;
                vp[0] = p01; vp[1] = p23; vp[2] = p45; vp[3] = p67;
            }
        }
        *(s8v*)(bt + p * CIPAD + ch8 * 8) = v;
    }

    const int n = lane & 31, half = lane >> 5;
    f32x16 acc0, acc1;
    #pragma unroll
    for (int i = 0; i < 16; i++) { acc0[i] = 0.f; acc1[i] = 0.f; }

    // ---- kc-outer: stage weight slice to LDS, then 9 taps of MFMA ----
    #pragma unroll
    for (int kc = 0; kc < KC; kc++) {
        if (kc) __syncthreads();               // previous ws readers done
        for (int i = tid; i < 1152; i += 512)
            ws[i] = apk[(size_t)kc * 1152 + i];
        __syncthreads();                       // ws ready (kc=0: also bt ready)
        #pragma unroll
        for (int ky = 0; ky < 3; ky++)
        #pragma unroll
        for (int kx = 0; kx < 3; kx++) {
            const int tap = ky * 3 + kx;
            s8v a0 = ws[tap * 128 + lane];
            s8v a1 = ws[tap * 128 + 64 + lane];
            const bf16_t* brow = bt + ((wv + ky) * 34 + n + kx) * CIPAD + half * 8;
            s8v bfrag = *(const s8v*)(brow + kc * 16);
            acc0 = __builtin_amdgcn_mfma_f32_32x32x16_bf16(a0, bfrag, acc0, 0, 0, 0);
            acc1 = __builtin_amdgcn_mfma_f32_32x32x16_bf16(a1, bfrag, acc1, 0, 0, 0);
        }
    }
    __syncthreads();   // bt/ws reads done; reuse bt as ot

    bf16_t* ot = bt;
    {
        const int pxl = wv * 32 + n;   // 0..255
        const bool pv = (x0 + n) < WW;
        #pragma unroll
        for (int g4 = 0; g4 < 4; g4++) {
            s4v pk0;
            #pragma unroll
            for (int jj = 0; jj < 4; jj++) {
                float v = acc0[g4 * 4 + jj];
                if (RELU) v = fmaxf(v, 0.f);
                pk0[jj] = (short)(pv ? f2b(v) : (bf16_t)0);
            }
            *(s4v*)&ot[pxl * OTS + g4 * 8 + 4 * half] = pk0;
            const int c1b = 32 + g4 * 8 + 4 * half;
            if (c1b + 3 < CO) {
                s4v pk1;
                #pragma unroll
                for (int jj = 0; jj < 4; jj++) {
                    float v = acc1[g4 * 4 + jj];
                    if (RELU) v = fmaxf(v, 0.f);
                    pk1[jj] = (short)(pv ? f2b(v) : (bf16_t)0);
                }
                *(s4v*)&ot[pxl * OTS + c1b] = pk1;
            }
        }
    }
    __syncthreads();
    {
        constexpr int NCH8 = 256 * CO / 8;
        for (int ch = tid; ch < NCH8; ch += 512) {
            int pxl = ch / (CO / 8);
            int co0 = (ch % (CO / 8)) * 8;
            int row = pxl >> 5, col = pxl & 31;
            int xx = x0 + col;
            if (xx < WW) {
                bf16_t* lp = &ot[pxl * OTS + co0];
                size_t ga = (((size_t)b * HH + y0 + row) * WW + xx) * CO + co0;
                if (ADDH) {
                    float4 h0 = ld4(hadd + ga), h1 = ld4(hadd + ga + 4);
                    float4 l0 = ld4(lp), l1 = ld4(lp + 4);
                    float4 v0 = make_float4(l0.x + h0.x, l0.y + h0.y, l0.z + h0.z, l0.w + h0.w);
                    float4 v1 = make_float4(l1.x + h1.x, l1.y + h1.y, l1.z + h1.z, l1.w + h1.w);
                    st4(out + ga, v0); st4(out + ga + 4, v1);
                    st4(lp, v0); st4(lp + 4, v1);
                } else {
                    *(ushort4*)(out + ga)     = *(ushort4*)lp;
                    *(ushort4*)(out + ga + 4) = *(ushort4*)(lp + 4);
                }
            }
        }
    }
    if (ADDH) __syncthreads();
    {
        constexpr int NPH = 512 / CO;
        const int c = tid % CO, rr = tid / CO;
        float s = 0.f, q = 0.f;
        if (rr < NPH) {
            for (int px = rr; px < 256; px += NPH) {
                float v = b2f(ot[px * OTS + c]);
                s += v; q += v * v;
            }
        }
        ss[tid] = s; qq[tid] = q;
        __syncthreads();
        if (tid < CO) {
            float S = ss[tid], Q = qq[tid];
            #pragma unroll
            for (int p = 1; p < NPH; p++) { S += ss[tid + p * CO]; Q += qq[tid + p * CO]; }
            ss[tid] = S; qq[tid] = Q;
        }
        __syncthreads();
        if (tid < NGRP) {
            float S = 0.f, Q = 0.f;
            #pragma unroll
            for (int j = 0; j < CG; j++) { S += ss[tid * CG + j]; Q += qq[tid * CG + j]; }
            unsafeAtomicAdd(&dsOut[((size_t)b * NGRP + tid) * 2],     (double)S);
            unsafeAtomicAdd(&dsOut[((size_t)b * NGRP + tid) * 2 + 1], (double)Q);
        }
    }
}

// ---------------- v = relu(z + gn2(u)) in place on u, looped + register group stats ----------
// (100,B) x 8 iters — R8 proved (200,B) regresses (same-address f64 atomic serialization).
__global__ __launch_bounds__(192) void add_relu_gn2_kernel(
    bf16_t* __restrict__ u, const bf16_t* __restrict__ z,
    const double* __restrict__ ds2, const float* __restrict__ g2,
    const float* __restrict__ b2, double* __restrict__ ds3)
{
    __shared__ float sm[16];
    const int tid = threadIdx.x;
    const int c0 = 8 * (tid % 6), pxr = tid / 6;
    const int b = blockIdx.y;
    if (tid < 16) sm[tid] = 0.f;
    const int gA = c0 / 6;
    const int split = (gA + 1) * 6 - c0;
    float meanA, invA, meanB, invB;
    ms_from(ds2, b * NGRP + gA,     1.0 / 153600.0, meanA, invA);
    ms_from(ds2, b * NGRP + gA + 1, 1.0 / 153600.0, meanB, invB);
    float wga[8], wbe[8];
    #pragma unroll
    for (int e = 0; e < 8; e++) {
        int c = c0 + e;
        float m = (e < split) ? meanA : meanB, iv = (e < split) ? invA : invB;
        float ga = g2[c] * iv;
        wga[e] = ga; wbe[e] = b2[c] - m * ga;
    }
    __syncthreads();
    const size_t pxbase = (size_t)b * HWSZ + (size_t)blockIdx.x * 256;
    float sA = 0.f, qA = 0.f, sB = 0.f, qB = 0.f;
    for (int it = 0; it < 8; it++) {
        size_t idx = (pxbase + it * 32 + pxr) * 48 + c0;
        float uu[8], zz[8], vv[8];
        ld8(u + idx, uu); ld8(z + idx, zz);
        #pragma unroll
        for (int e = 0; e < 8; e++) {
            float v = fmaxf(fmaf(uu[e], wga[e], wbe[e]) + zz[e], 0.f);
            vv[e] = v;
            if (e < split) { sA += v; qA += v * v; } else { sB += v; qB += v * v; }
        }
        st8(u + idx, vv);
    }
    atomicAdd(&sm[2 * gA], sA);     atomicAdd(&sm[2 * gA + 1], qA);
    atomicAdd(&sm[2 * gA + 2], sB); atomicAdd(&sm[2 * gA + 3], qB);
    __syncthreads();
    if (tid < NGRP) {
        unsafeAtomicAdd(&ds3[(b * NGRP + tid) * 2],     (double)sm[tid * 2]);
        unsafeAtomicAdd(&ds3[(b * NGRP + tid) * 2 + 1], (double)sm[tid * 2 + 1]);
    }
}

// ---------------- gn3 apply + fused Gram row, looped (MLP) ----------------
// (100,B) x 8 iters. Solve stays separate (R7 VGPR-poisoning lesson).
__global__ __launch_bounds__(192) void gn3_gram_kernel(
    const bf16_t* __restrict__ v, const bf16_t* __restrict__ z,
    bf16_t* __restrict__ F, bf16_t* __restrict__ G,
    const double* __restrict__ ds3, const float* __restrict__ g3,
    const float* __restrict__ b3,
    const bf16_t* __restrict__ Gall, int jslot, int nf, double* __restrict__ gram)
{
    __shared__ double red[3][5];
    const int tid = threadIdx.x;
    const int c0 = 8 * (tid % 6), pxr = tid / 6;
    const int b = blockIdx.y;
    const int gA = c0 / 6;
    const int split = (gA + 1) * 6 - c0;
    float meanA, invA, meanB, invB;
    ms_from(ds3, b * NGRP + gA,     1.0 / 153600.0, meanA, invA);
    ms_from(ds3, b * NGRP + gA + 1, 1.0 / 153600.0, meanB, invB);
    float wga[8], wbe[8];
    #pragma unroll
    for (int e = 0; e < 8; e++) {
        int c = c0 + e;
        float m = (e < split) ? meanA : meanB, iv = (e < split) ? invA : invB;
        float ga = g3[c] * iv;
        wga[e] = ga; wbe[e] = b3[c] - m * ga;
    }
    const size_t pxbase = (size_t)b * HWSZ + (size_t)blockIdx.x * 256;
    double dot[5] = {0.0, 0.0, 0.0, 0.0, 0.0};
    for (int it = 0; it < 8; it++) {
        size_t idx = (pxbase + it * 32 + pxr) * 48 + c0;
        float rr[8];
        ld8(v + idx, rr);
        #pragma unroll
        for (int e = 0; e < 8; e++) rr[e] = fmaf(rr[e], wga[e], wbe[e]);
        st8(F + idx, rr);
        if (nf > 0) {
            float zz[8], gg[8];
            ld8(z + idx, zz);
            #pragma unroll
            for (int e = 0; e < 8; e++) gg[e] = rr[e] - zz[e];
            st8(G + idx, gg);
            #pragma unroll
            for (int i = 0; i < 5; i++) {
                if (i >= nf) continue;
                float d = 0.f;
                if (i == jslot) {
                    #pragma unroll
                    for (int e = 0; e < 8; e++) d = fmaf(gg[e], gg[e], d);
                } else {
                    float gi[8];
                    ld8(Gall + (size_t)i * SLOT + idx, gi);
                    #pragma unroll
                    for (int e = 0; e < 8; e++) d = fmaf(gg[e], gi[e], d);
                }
                dot[i] += (double)d;
            }
        }
    }
    if (nf > 0) {
        #pragma unroll
        for (int i = 0; i < 5; i++) {
            if (i >= nf) continue;
            #pragma unroll
            for (int off = 32; off > 0; off >>= 1) dot[i] += __shfl_down(dot[i], off);
        }
        int wv = tid >> 6;
        if ((tid & 63) == 0) {
            #pragma unroll
            for (int i = 0; i < 5; i++) if (i < nf) red[wv][i] = dot[i];
        }
        __syncthreads();
        if (tid == 0) {
            #pragma unroll
            for (int i = 0; i < 5; i++) {
                if (i >= nf) continue;
                double D = red[0][i] + red[1][i] + red[2][i];
                unsafeAtomicAdd(&gram[b * 25 + jslot * 5 + i], D);
                if (i != jslot) unsafeAtomicAdd(&gram[b * 25 + i * 5 + jslot], D);
            }
        }
    }
}

// ---------------- Anderson solve (separate 1-block dispatch) ----------------
__global__ void solve_kernel(const double* __restrict__ gram, float* __restrict__ alpha, int n) {
    int b = threadIdx.x;
    if (b >= BB) return;
    const int m = n + 1;
    double A[6][7];
    for (int i = 0; i < m; i++)
        for (int jj = 0; jj <= m; jj++) A[i][jj] = 0.0;
    for (int i = 1; i < m; i++) { A[0][i] = 1.0; A[i][0] = 1.0; }
    for (int i = 1; i < m; i++)
        for (int jj = 1; jj < m; jj++)
            A[i][jj] = gram[b * 25 + (i - 1) * 5 + (jj - 1)] + ((i == jj) ? LAMV : 0.0);
    A[0][m] = 1.0;
    for (int col = 0; col < m; col++) {
        int piv = col; double best = fabs(A[col][col]);
        for (int rr = col + 1; rr < m; rr++) {
            double tv = fabs(A[rr][col]);
            if (tv > best) { best = tv; piv = rr; }
        }
        if (piv != col)
            for (int cc = col; cc <= m; cc++) {
                double tmp = A[col][cc]; A[col][cc] = A[piv][cc]; A[piv][cc] = tmp;
            }
        double invp = 1.0 / A[col][col];
        for (int cc = col; cc <= m; cc++) A[col][cc] *= invp;
        for (int rr = 0; rr < m; rr++) {
            if (rr == col) continue;
            double f = A[rr][col];
            if (f != 0.0)
                for (int cc = col; cc <= m; cc++) A[rr][cc] = fma(-f, A[col][cc], A[rr][cc]);
        }
    }
    for (int i = 0; i < n; i++) alpha[b * 5 + i] = (float)A[i + 1][m];
}

// xk = sum alpha_j F_j. Grid 2400 blocks x 2 iters.
// Block 0 zeroes gram row/col jz (post-solve, pre-gram accumulation).
__global__ __launch_bounds__(256) void xk_kernel(
    const bf16_t* __restrict__ Fb, const float* __restrict__ alpha,
    bf16_t* __restrict__ zcur, int n, double* __restrict__ gram, int jz, int nf)
{
    if (blockIdx.x == 0 && threadIdx.x < 8 * nf) {
        int b = threadIdx.x / nf, i = threadIdx.x % nf;
        gram[b * 25 + jz * 5 + i] = 0.0;
        gram[b * 25 + i * 5 + jz] = 0.0;
    }
    const int b = blockIdx.x / 300;
    float al[5];
    #pragma unroll
    for (int j = 0; j < 5; j++) al[j] = (j < n) ? alpha[b * 5 + j] : 0.f;
    const size_t base = (size_t)blockIdx.x * 4096 + (size_t)threadIdx.x * 8;
    for (int it = 0; it < 2; it++) {
        size_t idx = base + (size_t)it * 2048;
        float s[8] = {0.f, 0.f, 0.f, 0.f, 0.f, 0.f, 0.f, 0.f};
        #pragma unroll
        for (int j = 0; j < 5; j++) {
            if (j < n) {
                float f[8];
                ld8(Fb + (size_t)j * SLOT + idx, f);
                #pragma unroll
                for (int e = 0; e < 8; e++) s[e] = fmaf(f[e], al[j], s[e]);
            }
        }
        st8(zcur + idx, s);
    }
}

// ---------------- final linear (NHWC bf16 in) ----------------
__global__ __launch_bounds__(512) void fc_kernel(
    const bf16_t* __restrict__ zf, const float* __restrict__ fw,
    const float* __restrict__ fb, float* __restrict__ out)
{
    __shared__ bf16_t row[9600];
    __shared__ float fwT[2000];
    int tid = threadIdx.x;
    int b = blockIdx.x >> 7, hh = blockIdx.x & 127;
    size_t base = (((size_t)b * HH + hh) * WW) * 48;
    for (int i = tid; i < 2400; i += 512)
        *(ushort4*)&row[i * 4] = *(const ushort4*)(zf + base + (size_t)i * 4);
    for (int i = tid; i < 2000; i += 512) fwT[i] = fw[i];
    __syncthreads();
    if (tid < 480) {
        int c = tid % 48, o = tid / 48;
        float acc = fb[o];
        #pragma unroll 4
        for (int w = 0; w < 200; w++)
            acc = fmaf(b2f(row[w * 48 + c]), fwT[o * 200 + w], acc);
        out[(((size_t)b * 48 + c) * HH + hh) * 10 + o] = acc;
    }
}

// ---------------- host ----------------

static inline int imin(int a, int b) { return a < b ? a : b; }

extern "C" void kernel_launch(void* const* d_in, const int* in_sizes, int n_in,
                              void* d_out, int out_size, void* d_ws, size_t ws_size,
                              hipStream_t stream)
{
    const float* x   = (const float*)d_in[0];
    const float* w0  = (const float*)d_in[1];
    const float* b0  = (const float*)d_in[2];
    const float* bng = (const float*)d_in[3];
    const float* bnb = (const float*)d_in[4];
    const float* w1  = (const float*)d_in[5];
    const float* w2  = (const float*)d_in[6];
    const float* g1  = (const float*)d_in[7];
    const float* be1 = (const float*)d_in[8];
    const float* g2  = (const float*)d_in[9];
    const float* be2 = (const float*)d_in[10];
    const float* g3  = (const float*)d_in[11];
    const float* be3 = (const float*)d_in[12];
    const float* fcw = (const float*)d_in[13];
    const float* fcb = (const float*)d_in[14];
    float* out = (float*)d_out;

    bf16_t* h    = (bf16_t*)d_ws;           // SLOT    (NHWC)
    bf16_t* zcur = h + (size_t)SLOT;        // SLOT
    bf16_t* y64  = zcur + (size_t)SLOT;     // Y64SZ
    bf16_t* Fb   = y64 + (size_t)Y64SZ;     // 5*SLOT
    bf16_t* Gb   = Fb + 5 * (size_t)SLOT;   // 5*SLOT
    double* dstats = (double*)((char*)d_ws + BIGELEMS * 2);  // 9696 dbl: BN 96 + 25*384
    double* gram   = dstats + 9696;                          // 200 dbl
    float*  alpha  = (float*)(gram + 200);                   // 40 f
    double* bnbin  = (double*)(alpha + 40);                  // 768 dbl (8 bins x 96)
    bf16_t* apk1   = (bf16_t*)(bnbin + 768);                 // 27648
    bf16_t* apk2   = apk1 + 27648;                           // 36864
    bf16_t* scratch = Gb;  // conv0 raw bf16 (G region dead at that point)

    const size_t need = BIGELEMS * 2 + 9696 * 8 + 200 * 8 + 40 * 4 + 768 * 8
                        + (27648 + 36864) * 2;
    if (ws_size < need) return;

    const dim3 blk(256);
    const int CHUNKS16 = SLOT * 2 / 16 / 256;  // 4800

    // zero dstats + gram + alpha + bnbin = 9696*2 + 200*2 + 40 + 768*2 = 21368 floats
    zero_kernel<<<(21368 + 255) / 256, blk, 0, stream>>>((float*)dstats, 21368);
    pack_kernel<<<108, blk, 0, stream>>>(w1, apk1, 48, 64, 27648);
    pack_kernel<<<144, blk, 0, stream>>>(w2, apk2, 64, 48, 36864);
    fill16_kernel<<<CHUNKS16, blk, 0, stream>>>((float4*)zcur);

    // h = BN(conv0(x)+b0) in NHWC bf16; stats fused into conv0 (raw stored bf16)
    conv0_kernel<<<BB * HH, blk, 0, stream>>>(x, w0, b0, scratch, bnbin);
    bn_reduce_kernel<<<1, 128, 0, stream>>>(bnbin, dstats);
    bn_apply_kernel<<<SLOT / 2048, blk, 0, stream>>>(scratch, h, bng, bnb, dstats);

    int call = 0;
    auto resnet = [&](const bf16_t* zin, bf16_t* Fdst, bf16_t* Gdst, int jslot, int nf) {
        double* ds = dstats + 96 + 384 * call;  // ds1 = +0, ds2 = +128, ds3 = +256
        call++;
        dim3 cgv(7, 16, BB);
        conv_mfma_kernel<48, 56, 64, 66, 8, true, false, false><<<cgv, dim3(512), 0, stream>>>(
            zin, (const s8v*)apk1, nullptr, y64, ds, nullptr, nullptr, nullptr);
        conv_mfma_kernel<64, 72, 48, 50, 6, false, true, true><<<cgv, dim3(512), 0, stream>>>(
            y64, (const s8v*)apk2, h, Fdst, ds + 128, ds, g1, be1);
        add_relu_gn2_kernel<<<dim3(100, BB), dim3(192), 0, stream>>>(
            Fdst, zin, ds + 128, g2, be2, ds + 256);
        gn3_gram_kernel<<<dim3(100, BB), dim3(192), 0, stream>>>(
            Fdst, zin, Fdst, Gdst, ds + 256, g3, be3, Gb, jslot, nf, gram);
    };

    // slot 0: X=0, F0=f(0), G0=F0 (gram[0,0] accumulated in gn3)
    resnet(zcur, Fb, Gb, 0, 1);
    // slot 1: X=F0 -> zin IS Fb slot 0 (copy16 eliminated)
    resnet(Fb, Fb + (size_t)SLOT, Gb + (size_t)SLOT, 1, 2);

    for (int k = 2; k <= 24; k++) {
        int n = imin(k, 5);
        int j = k % 5;
        int nf = imin(k + 1, 5);
        solve_kernel<<<1, 64, 0, stream>>>(gram, alpha, n);
        xk_kernel<<<2400, blk, 0, stream>>>(Fb, alpha, zcur, n, gram, j, nf);
        if (k < 24)   // reference computes Fv at k=24 but never uses it
            resnet(zcur, Fb + (size_t)j * SLOT, Gb + (size_t)j * SLOT, j, nf);
    }

    // z_star = zcur; one extra f application into F slot 0 (no G, no gram)
    resnet(zcur, Fb, nullptr, 0, 0);

    // final linear: NHWC [8,128,200,48] x fw[10,200] -> out [8,48,128,10]
    fc_kernel<<<BB * HH, dim3(512), 0, stream>>>(Fb, fcw, fcb, out);
}

// Round 12
// 4640.231 us; speedup vs baseline: 1.0160x; 1.0160x over previous
//
#include <hip/hip_runtime.h>

#define BB   8
#define HH   128
#define WW   200
#define HWSZ 25600
#define C48  48
#define C64  64
#define NGRP 8
#define EPSV 1e-5f
#define LAMV 1e-4
#define SLOT 9830400          // BB*C48*HWSZ elements (one z/F/G slot)
#define DPB  1228800          // C48*HWSZ per-batch flat dim
#define Y64SZ 13107200        // BB*C64*HWSZ
#define BIGELEMS 131072000ull // 12*SLOT + Y64SZ

typedef unsigned short bf16_t;
typedef __attribute__((ext_vector_type(4))) short s4v;
typedef __attribute__((ext_vector_type(8))) short s8v;
typedef __attribute__((ext_vector_type(16))) float f32x16;

__device__ inline float b2f(bf16_t b) { return __uint_as_float(((unsigned)b) << 16); }
__device__ inline bf16_t f2b(float f) {
    unsigned u = __float_as_uint(f);
    unsigned r = u + 0x7fffu + ((u >> 16) & 1u);
    return (bf16_t)(r >> 16);
}
__device__ inline float lo16(unsigned u) { return __uint_as_float(u << 16); }
__device__ inline float hi16(unsigned u) { return __uint_as_float(u & 0xffff0000u); }
__device__ inline unsigned pack2(float lo, float hi) {
    return ((unsigned)f2b(lo)) | (((unsigned)f2b(hi)) << 16);
}
__device__ inline float4 ld4(const bf16_t* p) {
    ushort4 u = *(const ushort4*)p;
    return make_float4(b2f(u.x), b2f(u.y), b2f(u.z), b2f(u.w));
}
__device__ inline void st4(bf16_t* p, float4 v) {
    ushort4 u; u.x = f2b(v.x); u.y = f2b(v.y); u.z = f2b(v.z); u.w = f2b(v.w);
    *(ushort4*)p = u;
}
// 8 bf16 <-> 8 floats via one 16B op
__device__ inline void ld8(const bf16_t* p, float* v) {
    uint4 u = *(const uint4*)p;
    v[0] = lo16(u.x); v[1] = hi16(u.x); v[2] = lo16(u.y); v[3] = hi16(u.y);
    v[4] = lo16(u.z); v[5] = hi16(u.z); v[6] = lo16(u.w); v[7] = hi16(u.w);
}
__device__ inline void st8(bf16_t* p, const float* v) {
    uint4 u;
    u.x = pack2(v[0], v[1]); u.y = pack2(v[2], v[3]);
    u.z = pack2(v[4], v[5]); u.w = pack2(v[6], v[7]);
    *(uint4*)p = u;
}

// (mean, invstd) from f64 sums at use site
__device__ inline void ms_from(const double* __restrict__ ds, int pair, double invcnt,
                               float& mean, float& inv) {
    double s = ds[2 * pair], q = ds[2 * pair + 1];
    double m = s * invcnt;
    double v = q * invcnt - m * m;
    mean = (float)m;
    inv = (float)(1.0 / sqrt(v + (double)EPSV));
}

// ---------------- utility ----------------

__global__ void zero_kernel(float* __restrict__ p, int n) {
    int i = blockIdx.x * 256 + threadIdx.x;
    if (i < n) p[i] = 0.f;
}
__global__ void fill16_kernel(float4* __restrict__ p) {
    float4 z; z.x = z.y = z.z = z.w = 0.f;
    p[(size_t)blockIdx.x * 256 + threadIdx.x] = z;
}

// ---------------- weight packing: [kc][tap][mt][lane][8] bf16 ----------------
__global__ void pack_kernel(const float* __restrict__ w, bf16_t* __restrict__ apk,
                            int CIN, int CO_real, int total) {
    int idx = blockIdx.x * 256 + threadIdx.x;
    if (idx >= total) return;
    int j   = idx & 7;
    int l   = (idx >> 3) & 63;
    int mt  = (idx >> 9) & 1;
    int tap = (idx >> 10) % 9;
    int kc  = idx / 9216;
    int co = mt * 32 + (l & 31);
    int ci = kc * 16 + (l >> 5) * 8 + j;
    float v = (co < CO_real) ? w[((size_t)co * CIN + ci) * 9 + tap] : 0.f;
    apk[idx] = f2b(v);
}

// ---------------- conv0 (1->48) + fused BN stats (R9-proven) ----------------
__global__ __launch_bounds__(256) void conv0_kernel(
    const float* __restrict__ x, const float* __restrict__ w0,
    const float* __restrict__ b0, float* __restrict__ out,
    double* __restrict__ bnbin)
{
    __shared__ float xs[3 * 202];
    __shared__ float wt[480];
    __shared__ float ss[48], qq[48];
    const int tid = threadIdx.x;
    const int bI = blockIdx.x / HH, y = blockIdx.x % HH;
    for (int i = tid; i < 606; i += 256) {
        int r = i / 202, cc = i % 202;
        int gy = y + r - 1, gx = cc - 1;
        float v = 0.f;
        if ((unsigned)gy < (unsigned)HH && (unsigned)gx < (unsigned)WW)
            v = x[(size_t)bI * HWSZ + gy * WW + gx];
        xs[r * 202 + cc] = v;
    }
    for (int i = tid; i < 480; i += 256) wt[i] = (i < 432) ? w0[i] : b0[i - 432];
    if (tid < 48) { ss[tid] = 0.f; qq[tid] = 0.f; }
    __syncthreads();
    const size_t obase = (((size_t)bI * HH + y) * WW) * 48;
    float4 sacc[3], qacc[3];
    #pragma unroll
    for (int j = 0; j < 3; j++) {
        sacc[j] = make_float4(0.f, 0.f, 0.f, 0.f);
        qacc[j] = make_float4(0.f, 0.f, 0.f, 0.f);
    }
    int k3 = 0;
    for (int ch = tid; ch < 2400; ch += 256) {
        int px = (ch * 4) / 48, c0 = (ch * 4) % 48;
        float xv[3][3];
        #pragma unroll
        for (int r = 0; r < 3; r++)
            #pragma unroll
            for (int dx = 0; dx < 3; dx++)
                xv[r][dx] = xs[r * 202 + px + dx];
        float4 o;
        #pragma unroll
        for (int j = 0; j < 4; j++) {
            int c = c0 + j;
            float acc = wt[432 + c];
            #pragma unroll
            for (int r = 0; r < 3; r++)
                #pragma unroll
                for (int dx = 0; dx < 3; dx++)
                    acc = fmaf(xv[r][dx], wt[c * 9 + r * 3 + dx], acc);
            ((float*)&o)[j] = acc;
        }
        *(float4*)(out + obase + ch * 4) = o;
        sacc[k3].x += o.x; sacc[k3].y += o.y; sacc[k3].z += o.z; sacc[k3].w += o.w;
        qacc[k3].x = fmaf(o.x, o.x, qacc[k3].x);
        qacc[k3].y = fmaf(o.y, o.y, qacc[k3].y);
        qacc[k3].z = fmaf(o.z, o.z, qacc[k3].z);
        qacc[k3].w = fmaf(o.w, o.w, qacc[k3].w);
        k3 = (k3 == 2) ? 0 : k3 + 1;
    }
    #pragma unroll
    for (int j = 0; j < 3; j++) {
        int quad = (tid + 4 * j) % 12;
        atomicAdd(&ss[quad * 4 + 0], sacc[j].x);
        atomicAdd(&ss[quad * 4 + 1], sacc[j].y);
        atomicAdd(&ss[quad * 4 + 2], sacc[j].z);
        atomicAdd(&ss[quad * 4 + 3], sacc[j].w);
        atomicAdd(&qq[quad * 4 + 0], qacc[j].x);
        atomicAdd(&qq[quad * 4 + 1], qacc[j].y);
        atomicAdd(&qq[quad * 4 + 2], qacc[j].z);
        atomicAdd(&qq[quad * 4 + 3], qacc[j].w);
    }
    __syncthreads();
    if (tid < 48) {
        int bin = blockIdx.x & 7;
        unsafeAtomicAdd(&bnbin[bin * 96 + tid * 2],     (double)ss[tid]);
        unsafeAtomicAdd(&bnbin[bin * 96 + tid * 2 + 1], (double)qq[tid]);
    }
}

// 1-block: dstats[0..95] = sum of 8 bins
__global__ void bn_reduce_kernel(const double* __restrict__ bnbin, double* __restrict__ dst) {
    int t = threadIdx.x;
    if (t < 96) {
        double s = 0.0;
        #pragma unroll
        for (int j = 0; j < 8; j++) s += bnbin[j * 96 + t];
        dst[t] = s;
    }
}

// ---------------- BN apply: fp32 NHWC raw -> bf16 NHWC h ----------------
__global__ __launch_bounds__(256) void bn_apply_kernel(
    const float* __restrict__ src, bf16_t* __restrict__ dst,
    const float* __restrict__ gamma, const float* __restrict__ beta,
    const double* __restrict__ ds)
{
    __shared__ float gaT[48], beT[48];
    int tid = threadIdx.x;
    if (tid < 48) {
        float mean, inv; ms_from(ds, tid, 1.0 / 204800.0, mean, inv);
        float ga = gamma[tid] * inv;
        gaT[tid] = ga; beT[tid] = beta[tid] - mean * ga;
    }
    __syncthreads();
    size_t base = (size_t)blockIdx.x * 1024 + (size_t)tid * 4;
    int c0 = (int)(base % 48);
    float4 v = *(const float4*)(src + base);
    ushort4 o;
    o.x = f2b(fmaf(v.x, gaT[c0],     beT[c0]));
    o.y = f2b(fmaf(v.y, gaT[c0 + 1], beT[c0 + 1]));
    o.z = f2b(fmaf(v.z, gaT[c0 + 2], beT[c0 + 2]));
    o.w = f2b(fmaf(v.w, gaT[c0 + 3], beT[c0 + 3]));
    *(ushort4*)(dst + base) = o;
}

// ---------------- MFMA implicit-GEMM 3x3 conv (R5/R9 structure) ----------------
// R12: FUSEXK path — conv1 stages z = sum_j alpha_j * F_j IN-REGISTER from the 5 F
// slots (replacing the standalone xk dispatch: 23 launches x ~30µs + 40MB z round-trip
// per iter). The bf16-packed z is written to bt (MFMA B-operand), and tile-INTERIOR
// items (r in [1,8], c in [1,32]) are stored to zcur (each 16B written exactly once;
// gn2/gn3 read zcur later — stream-ordered). Math identical to xk: f32 fmaf ladder,
// one bf16 round. Gram zeroing moved to solve_kernel tail.
template<int CIN, int CIPAD, int CO, int OTS, int CG, bool RELU, bool ADDH, bool FOLDGN,
         bool FUSEXK>
__global__ __launch_bounds__(512, 4) void conv_mfma_kernel(
    const bf16_t* __restrict__ in, const s8v* __restrict__ apk,
    const bf16_t* __restrict__ hadd, bf16_t* __restrict__ out,
    double* __restrict__ dsOut,
    const double* __restrict__ dsPrev, const float* __restrict__ gPrev,
    const float* __restrict__ bPrev,
    const bf16_t* __restrict__ FbX, const float* __restrict__ alphaX,
    bf16_t* __restrict__ zwr, int nX)
{
    constexpr int KC  = CIN / 16;
    constexpr int NC8 = CIN / 8;
    constexpr int NITEMS = 10 * 34 * NC8;
    constexpr int NIT = (NITEMS + 511) / 512;
    const int tid  = threadIdx.x;
    const int lane = tid & 63;
    const int wv   = tid >> 6;          // 0..7 = output row within block
    const int x0 = blockIdx.x * 32;
    const int y0 = blockIdx.y * 8;
    const int b  = blockIdx.z;

    __shared__ __align__(16) bf16_t bt[10 * 34 * CIPAD];  // reused as ot[256][OTS]
    __shared__ __align__(16) s8v ws[1152];                // one kc-slice of apk (18.4KB)
    __shared__ __align__(16) float gaT[FOLDGN ? CIN : 4];
    __shared__ __align__(16) float beT[FOLDGN ? CIN : 4];
    __shared__ float ss[512], qq[512];

    if (FOLDGN) {
        if (tid < CIN) {
            float mean, inv;
            ms_from(dsPrev, b * NGRP + tid / (CIN / NGRP), 1.0 / 204800.0, mean, inv);
            float ga = gPrev[tid] * inv;
            gaT[tid] = ga; beT[tid] = bPrev[tid] - mean * ga;
        }
        __syncthreads();
    }

    if (FUSEXK) {
        // ---- fused xk + staging: z tile formed from 5 F slots, written to bt + zcur ----
        float al[5];
        #pragma unroll
        for (int j = 0; j < 5; j++) al[j] = (j < nX) ? alphaX[b * 5 + j] : 0.f;
        for (int k = 0; k < NIT; k++) {
            int i = tid + k * 512;
            if (i >= NITEMS) continue;
            int ch8 = i % NC8, p = i / NC8;
            int r = p / 34, c = p - r * 34;
            int gy = y0 + r - 1, gx = x0 + c - 1;
            s8v v;
            #pragma unroll
            for (int e = 0; e < 8; e++) v[e] = 0;
            if ((unsigned)gy < (unsigned)HH && (unsigned)gx < (unsigned)WW) {
                size_t gidx = (((size_t)b * HH + gy) * WW + gx) * CIN + ch8 * 8;
                float zf[8] = {0.f, 0.f, 0.f, 0.f, 0.f, 0.f, 0.f, 0.f};
                #pragma unroll
                for (int j = 0; j < 5; j++) {
                    if (j < nX) {
                        float f[8];
                        ld8(FbX + (size_t)j * SLOT + gidx, f);
                        #pragma unroll
                        for (int e = 0; e < 8; e++) zf[e] = fmaf(f[e], al[j], zf[e]);
                    }
                }
                uint4 upk;
                upk.x = pack2(zf[0], zf[1]); upk.y = pack2(zf[2], zf[3]);
                upk.z = pack2(zf[4], zf[5]); upk.w = pack2(zf[6], zf[7]);
                v = *(s8v*)&upk;
                if (r >= 1 && r <= 8 && c >= 1 && c <= 32)
                    *(s8v*)(zwr + gidx) = v;    // interior: each 16B written once
            }
            *(s8v*)(bt + p * CIPAD + ch8 * 8) = v;
        }
    } else {
        // ---- input staging, batched: issue all loads, single wait, then fold+write ----
        s8v vreg[NIT];
        #pragma unroll
        for (int k = 0; k < NIT; k++) {
            int i = tid + k * 512;
            s8v t;
            #pragma unroll
            for (int e = 0; e < 8; e++) t[e] = 0;
            if (i < NITEMS) {
                int ch8 = i % NC8, p = i / NC8;
                int r = p / 34, c = p - r * 34;
                int gy = y0 + r - 1, gx = x0 + c - 1;
                if ((unsigned)gy < (unsigned)HH && (unsigned)gx < (unsigned)WW)
                    t = *(const s8v*)(in + ((((size_t)b * HH + gy) * WW + gx) * CIN + ch8 * 8));
            }
            vreg[k] = t;
        }
        #pragma unroll
        for (int k = 0; k < NIT; k++) {
            int i = tid + k * 512;
            if (i >= NITEMS) continue;
            int ch8 = i % NC8, p = i / NC8;
            s8v v = vreg[k];
            if (FOLDGN) {
                int r = p / 34, c = p - r * 34;
                int gy = y0 + r - 1, gx = x0 + c - 1;
                if ((unsigned)gy < (unsigned)HH && (unsigned)gx < (unsigned)WW) {
                    const float* ga8 = &gaT[ch8 * 8];
                    const float* be8 = &beT[ch8 * 8];
                    float f[8];
                    #pragma unroll
                    for (int e = 0; e < 8; e++)
                        f[e] = fmaf(b2f((bf16_t)(unsigned short)v[e]), ga8[e], be8[e]);
                    unsigned p01, p23, p45, p67;
                    asm("v_cvt_pk_bf16_f32 %0, %1, %2" : "=v"(p01) : "v"(f[0]), "v"(f[1]));
                    asm("v_cvt_pk_bf16_f32 %0, %1, %2" : "=v"(p23) : "v"(f[2]), "v"(f[3]));
                    asm("v_cvt_pk_bf16_f32 %0, %1, %2" : "=v"(p45) : "v"(f[4]), "v"(f[5]));
                    asm("v_cvt_pk_bf16_f32 %0, %1, %2" : "=v"(p67) : "v"(f[6]), "v"(f[7]));
                    unsigned* vp = (unsigned*)&v;
                    vp[0] = p01; vp[1] = p23; vp[2] = p45; vp[3] = p67;
                }
            }
            *(s8v*)(bt + p * CIPAD + ch8 * 8) = v;
        }
    }

    const int n = lane & 31, half = lane >> 5;
    f32x16 acc0, acc1;
    #pragma unroll
    for (int i = 0; i < 16; i++) { acc0[i] = 0.f; acc1[i] = 0.f; }

    // ---- kc-outer: stage weight slice to LDS, then 9 taps of MFMA ----
    #pragma unroll
    for (int kc = 0; kc < KC; kc++) {
        if (kc) __syncthreads();               // previous ws readers done
        for (int i = tid; i < 1152; i += 512)
            ws[i] = apk[(size_t)kc * 1152 + i];
        __syncthreads();                       // ws ready (kc=0: also bt ready)
        #pragma unroll
        for (int ky = 0; ky < 3; ky++)
        #pragma unroll
        for (int kx = 0; kx < 3; kx++) {
            const int tap = ky * 3 + kx;
            s8v a0 = ws[tap * 128 + lane];
            s8v a1 = ws[tap * 128 + 64 + lane];
            const bf16_t* brow = bt + ((wv + ky) * 34 + n + kx) * CIPAD + half * 8;
            s8v bfrag = *(const s8v*)(brow + kc * 16);
            acc0 = __builtin_amdgcn_mfma_f32_32x32x16_bf16(a0, bfrag, acc0, 0, 0, 0);
            acc1 = __builtin_amdgcn_mfma_f32_32x32x16_bf16(a1, bfrag, acc1, 0, 0, 0);
        }
    }
    __syncthreads();   // bt/ws reads done; reuse bt as ot

    bf16_t* ot = bt;
    {
        const int pxl = wv * 32 + n;   // 0..255
        const bool pv = (x0 + n) < WW;
        #pragma unroll
        for (int g4 = 0; g4 < 4; g4++) {
            s4v pk0;
            #pragma unroll
            for (int jj = 0; jj < 4; jj++) {
                float v = acc0[g4 * 4 + jj];
                if (RELU) v = fmaxf(v, 0.f);
                pk0[jj] = (short)(pv ? f2b(v) : (bf16_t)0);
            }
            *(s4v*)&ot[pxl * OTS + g4 * 8 + 4 * half] = pk0;
            const int c1b = 32 + g4 * 8 + 4 * half;
            if (c1b + 3 < CO) {
                s4v pk1;
                #pragma unroll
                for (int jj = 0; jj < 4; jj++) {
                    float v = acc1[g4 * 4 + jj];
                    if (RELU) v = fmaxf(v, 0.f);
                    pk1[jj] = (short)(pv ? f2b(v) : (bf16_t)0);
                }
                *(s4v*)&ot[pxl * OTS + c1b] = pk1;
            }
        }
    }
    __syncthreads();
    {
        constexpr int NCH8 = 256 * CO / 8;
        for (int ch = tid; ch < NCH8; ch += 512) {
            int pxl = ch / (CO / 8);
            int co0 = (ch % (CO / 8)) * 8;
            int row = pxl >> 5, col = pxl & 31;
            int xx = x0 + col;
            if (xx < WW) {
                bf16_t* lp = &ot[pxl * OTS + co0];
                size_t ga = (((size_t)b * HH + y0 + row) * WW + xx) * CO + co0;
                if (ADDH) {
                    float4 h0 = ld4(hadd + ga), h1 = ld4(hadd + ga + 4);
                    float4 l0 = ld4(lp), l1 = ld4(lp + 4);
                    float4 v0 = make_float4(l0.x + h0.x, l0.y + h0.y, l0.z + h0.z, l0.w + h0.w);
                    float4 v1 = make_float4(l1.x + h1.x, l1.y + h1.y, l1.z + h1.z, l1.w + h1.w);
                    st4(out + ga, v0); st4(out + ga + 4, v1);
                    st4(lp, v0); st4(lp + 4, v1);
                } else {
                    *(ushort4*)(out + ga)     = *(ushort4*)lp;
                    *(ushort4*)(out + ga + 4) = *(ushort4*)(lp + 4);
                }
            }
        }
    }
    if (ADDH) __syncthreads();
    {
        constexpr int NPH = 512 / CO;
        const int c = tid % CO, rr = tid / CO;
        float s = 0.f, q = 0.f;
        if (rr < NPH) {
            for (int px = rr; px < 256; px += NPH) {
                float v = b2f(ot[px * OTS + c]);
                s += v; q += v * v;
            }
        }
        ss[tid] = s; qq[tid] = q;
        __syncthreads();
        if (tid < CO) {
            float S = ss[tid], Q = qq[tid];
            #pragma unroll
            for (int p = 1; p < NPH; p++) { S += ss[tid + p * CO]; Q += qq[tid + p * CO]; }
            ss[tid] = S; qq[tid] = Q;
        }
        __syncthreads();
        if (tid < NGRP) {
            float S = 0.f, Q = 0.f;
            #pragma unroll
            for (int j = 0; j < CG; j++) { S += ss[tid * CG + j]; Q += qq[tid * CG + j]; }
            unsafeAtomicAdd(&dsOut[((size_t)b * NGRP + tid) * 2],     (double)S);
            unsafeAtomicAdd(&dsOut[((size_t)b * NGRP + tid) * 2 + 1], (double)Q);
        }
    }
}

// ---------------- v = relu(z + gn2(u)) in place on u, looped + register group stats ----------
// (100,B) x 8 iters — R8 proved (200,B) regresses (same-address f64 atomic serialization).
__global__ __launch_bounds__(192) void add_relu_gn2_kernel(
    bf16_t* __restrict__ u, const bf16_t* __restrict__ z,
    const double* __restrict__ ds2, const float* __restrict__ g2,
    const float* __restrict__ b2, double* __restrict__ ds3)
{
    __shared__ float sm[16];
    const int tid = threadIdx.x;
    const int c0 = 8 * (tid % 6), pxr = tid / 6;
    const int b = blockIdx.y;
    if (tid < 16) sm[tid] = 0.f;
    const int gA = c0 / 6;
    const int split = (gA + 1) * 6 - c0;
    float meanA, invA, meanB, invB;
    ms_from(ds2, b * NGRP + gA,     1.0 / 153600.0, meanA, invA);
    ms_from(ds2, b * NGRP + gA + 1, 1.0 / 153600.0, meanB, invB);
    float wga[8], wbe[8];
    #pragma unroll
    for (int e = 0; e < 8; e++) {
        int c = c0 + e;
        float m = (e < split) ? meanA : meanB, iv = (e < split) ? invA : invB;
        float ga = g2[c] * iv;
        wga[e] = ga; wbe[e] = b2[c] - m * ga;
    }
    __syncthreads();
    const size_t pxbase = (size_t)b * HWSZ + (size_t)blockIdx.x * 256;
    float sA = 0.f, qA = 0.f, sB = 0.f, qB = 0.f;
    for (int it = 0; it < 8; it++) {
        size_t idx = (pxbase + it * 32 + pxr) * 48 + c0;
        float uu[8], zz[8], vv[8];
        ld8(u + idx, uu); ld8(z + idx, zz);
        #pragma unroll
        for (int e = 0; e < 8; e++) {
            float v = fmaxf(fmaf(uu[e], wga[e], wbe[e]) + zz[e], 0.f);
            vv[e] = v;
            if (e < split) { sA += v; qA += v * v; } else { sB += v; qB += v * v; }
        }
        st8(u + idx, vv);
    }
    atomicAdd(&sm[2 * gA], sA);     atomicAdd(&sm[2 * gA + 1], qA);
    atomicAdd(&sm[2 * gA + 2], sB); atomicAdd(&sm[2 * gA + 3], qB);
    __syncthreads();
    if (tid < NGRP) {
        unsafeAtomicAdd(&ds3[(b * NGRP + tid) * 2],     (double)sm[tid * 2]);
        unsafeAtomicAdd(&ds3[(b * NGRP + tid) * 2 + 1], (double)sm[tid * 2 + 1]);
    }
}

// ---------------- gn3 apply + fused Gram row, looped (MLP) ----------------
// (100,B) x 8 iters. Solve stays separate (R7 VGPR-poisoning lesson).
__global__ __launch_bounds__(192) void gn3_gram_kernel(
    const bf16_t* __restrict__ v, const bf16_t* __restrict__ z,
    bf16_t* __restrict__ F, bf16_t* __restrict__ G,
    const double* __restrict__ ds3, const float* __restrict__ g3,
    const float* __restrict__ b3,
    const bf16_t* __restrict__ Gall, int jslot, int nf, double* __restrict__ gram)
{
    __shared__ double red[3][5];
    const int tid = threadIdx.x;
    const int c0 = 8 * (tid % 6), pxr = tid / 6;
    const int b = blockIdx.y;
    const int gA = c0 / 6;
    const int split = (gA + 1) * 6 - c0;
    float meanA, invA, meanB, invB;
    ms_from(ds3, b * NGRP + gA,     1.0 / 153600.0, meanA, invA);
    ms_from(ds3, b * NGRP + gA + 1, 1.0 / 153600.0, meanB, invB);
    float wga[8], wbe[8];
    #pragma unroll
    for (int e = 0; e < 8; e++) {
        int c = c0 + e;
        float m = (e < split) ? meanA : meanB, iv = (e < split) ? invA : invB;
        float ga = g3[c] * iv;
        wga[e] = ga; wbe[e] = b3[c] - m * ga;
    }
    const size_t pxbase = (size_t)b * HWSZ + (size_t)blockIdx.x * 256;
    double dot[5] = {0.0, 0.0, 0.0, 0.0, 0.0};
    for (int it = 0; it < 8; it++) {
        size_t idx = (pxbase + it * 32 + pxr) * 48 + c0;
        float rr[8];
        ld8(v + idx, rr);
        #pragma unroll
        for (int e = 0; e < 8; e++) rr[e] = fmaf(rr[e], wga[e], wbe[e]);
        st8(F + idx, rr);
        if (nf > 0) {
            float zz[8], gg[8];
            ld8(z + idx, zz);
            #pragma unroll
            for (int e = 0; e < 8; e++) gg[e] = rr[e] - zz[e];
            st8(G + idx, gg);
            #pragma unroll
            for (int i = 0; i < 5; i++) {
                if (i >= nf) continue;
                float d = 0.f;
                if (i == jslot) {
                    #pragma unroll
                    for (int e = 0; e < 8; e++) d = fmaf(gg[e], gg[e], d);
                } else {
                    float gi[8];
                    ld8(Gall + (size_t)i * SLOT + idx, gi);
                    #pragma unroll
                    for (int e = 0; e < 8; e++) d = fmaf(gg[e], gi[e], d);
                }
                dot[i] += (double)d;
            }
        }
    }
    if (nf > 0) {
        #pragma unroll
        for (int i = 0; i < 5; i++) {
            if (i >= nf) continue;
            #pragma unroll
            for (int off = 32; off > 0; off >>= 1) dot[i] += __shfl_down(dot[i], off);
        }
        int wv = tid >> 6;
        if ((tid & 63) == 0) {
            #pragma unroll
            for (int i = 0; i < 5; i++) if (i < nf) red[wv][i] = dot[i];
        }
        __syncthreads();
        if (tid == 0) {
            #pragma unroll
            for (int i = 0; i < 5; i++) {
                if (i >= nf) continue;
                double D = red[0][i] + red[1][i] + red[2][i];
                unsafeAtomicAdd(&gram[b * 25 + jslot * 5 + i], D);
                if (i != jslot) unsafeAtomicAdd(&gram[b * 25 + i * 5 + jslot], D);
            }
        }
    }
}

// ---------------- Anderson solve + gram row/col zeroing (was in xk) ----------------
// Each thread b reads its gram block into registers FIRST, then zeroes its own
// row/col jz — per-thread ordering suffices (no cross-thread gram use).
__global__ void solve_kernel(double* __restrict__ gram, float* __restrict__ alpha,
                             int n, int jz, int nf) {
    int b = threadIdx.x;
    if (b >= BB) return;
    const int m = n + 1;
    double A[6][7];
    for (int i = 0; i < m; i++)
        for (int jj = 0; jj <= m; jj++) A[i][jj] = 0.0;
    for (int i = 1; i < m; i++) { A[0][i] = 1.0; A[i][0] = 1.0; }
    for (int i = 1; i < m; i++)
        for (int jj = 1; jj < m; jj++)
            A[i][jj] = gram[b * 25 + (i - 1) * 5 + (jj - 1)] + ((i == jj) ? LAMV : 0.0);
    A[0][m] = 1.0;
    for (int col = 0; col < m; col++) {
        int piv = col; double best = fabs(A[col][col]);
        for (int rr = col + 1; rr < m; rr++) {
            double tv = fabs(A[rr][col]);
            if (tv > best) { best = tv; piv = rr; }
        }
        if (piv != col)
            for (int cc = col; cc <= m; cc++) {
                double tmp = A[col][cc]; A[col][cc] = A[piv][cc]; A[piv][cc] = tmp;
            }
        double invp = 1.0 / A[col][col];
        for (int cc = col; cc <= m; cc++) A[col][cc] *= invp;
        for (int rr = 0; rr < m; rr++) {
            if (rr == col) continue;
            double f = A[rr][col];
            if (f != 0.0)
                for (int cc = col; cc <= m; cc++) A[rr][cc] = fma(-f, A[col][cc], A[rr][cc]);
        }
    }
    for (int i = 0; i < n; i++) alpha[b * 5 + i] = (float)A[i + 1][m];
    for (int i = 0; i < nf; i++) {
        gram[b * 25 + jz * 5 + i] = 0.0;
        gram[b * 25 + i * 5 + jz] = 0.0;
    }
}

// ---------------- final linear (NHWC bf16 in) ----------------
__global__ __launch_bounds__(512) void fc_kernel(
    const bf16_t* __restrict__ zf, const float* __restrict__ fw,
    const float* __restrict__ fb, float* __restrict__ out)
{
    __shared__ bf16_t row[9600];
    __shared__ float fwT[2000];
    int tid = threadIdx.x;
    int b = blockIdx.x >> 7, hh = blockIdx.x & 127;
    size_t base = (((size_t)b * HH + hh) * WW) * 48;
    for (int i = tid; i < 2400; i += 512)
        *(ushort4*)&row[i * 4] = *(const ushort4*)(zf + base + (size_t)i * 4);
    for (int i = tid; i < 2000; i += 512) fwT[i] = fw[i];
    __syncthreads();
    if (tid < 480) {
        int c = tid % 48, o = tid / 48;
        float acc = fb[o];
        #pragma unroll 4
        for (int w = 0; w < 200; w++)
            acc = fmaf(b2f(row[w * 48 + c]), fwT[o * 200 + w], acc);
        out[(((size_t)b * 48 + c) * HH + hh) * 10 + o] = acc;
    }
}

// ---------------- host ----------------

static inline int imin(int a, int b) { return a < b ? a : b; }

extern "C" void kernel_launch(void* const* d_in, const int* in_sizes, int n_in,
                              void* d_out, int out_size, void* d_ws, size_t ws_size,
                              hipStream_t stream)
{
    const float* x   = (const float*)d_in[0];
    const float* w0  = (const float*)d_in[1];
    const float* b0  = (const float*)d_in[2];
    const float* bng = (const float*)d_in[3];
    const float* bnb = (const float*)d_in[4];
    const float* w1  = (const float*)d_in[5];
    const float* w2  = (const float*)d_in[6];
    const float* g1  = (const float*)d_in[7];
    const float* be1 = (const float*)d_in[8];
    const float* g2  = (const float*)d_in[9];
    const float* be2 = (const float*)d_in[10];
    const float* g3  = (const float*)d_in[11];
    const float* be3 = (const float*)d_in[12];
    const float* fcw = (const float*)d_in[13];
    const float* fcb = (const float*)d_in[14];
    float* out = (float*)d_out;

    bf16_t* h    = (bf16_t*)d_ws;           // SLOT    (NHWC)
    bf16_t* zcur = h + (size_t)SLOT;        // SLOT
    bf16_t* y64  = zcur + (size_t)SLOT;     // Y64SZ
    bf16_t* Fb   = y64 + (size_t)Y64SZ;     // 5*SLOT
    bf16_t* Gb   = Fb + 5 * (size_t)SLOT;   // 5*SLOT
    double* dstats = (double*)((char*)d_ws + BIGELEMS * 2);  // 9696 dbl: BN 96 + 25*384
    double* gram   = dstats + 9696;                          // 200 dbl
    float*  alpha  = (float*)(gram + 200);                   // 40 f
    double* bnbin  = (double*)(alpha + 40);                  // 768 dbl (8 bins x 96)
    bf16_t* apk1   = (bf16_t*)(bnbin + 768);                 // 27648
    bf16_t* apk2   = apk1 + 27648;                           // 36864
    float*  scratch = (float*)Gb;  // conv0 raw fp32 (G region dead at that point)

    const size_t need = BIGELEMS * 2 + 9696 * 8 + 200 * 8 + 40 * 4 + 768 * 8
                        + (27648 + 36864) * 2;
    if (ws_size < need) return;

    const dim3 blk(256);
    const int CHUNKS16 = SLOT * 2 / 16 / 256;  // 4800

    // zero dstats + gram + alpha + bnbin = 9696*2 + 200*2 + 40 + 768*2 = 21368 floats
    zero_kernel<<<(21368 + 255) / 256, blk, 0, stream>>>((float*)dstats, 21368);
    pack_kernel<<<108, blk, 0, stream>>>(w1, apk1, 48, 64, 27648);
    pack_kernel<<<144, blk, 0, stream>>>(w2, apk2, 64, 48, 36864);
    fill16_kernel<<<CHUNKS16, blk, 0, stream>>>((float4*)zcur);

    // h = BN(conv0(x)+b0) in NHWC bf16; stats fused into conv0, 8-way binned
    conv0_kernel<<<BB * HH, blk, 0, stream>>>(x, w0, b0, scratch, bnbin);
    bn_reduce_kernel<<<1, 128, 0, stream>>>(bnbin, dstats);
    bn_apply_kernel<<<SLOT / 1024, blk, 0, stream>>>(scratch, h, bng, bnb, dstats);

    int call = 0;
    // fused=false: zin staged directly. fused=true: conv1 forms z from (Fb, alpha, n)
    // in-register, writes zcur interior, and uses it as the MFMA B-operand.
    auto resnet = [&](const bf16_t* zin, bf16_t* Fdst, bf16_t* Gdst, int jslot, int nf,
                      bool fused, int nX) {
        double* ds = dstats + 96 + 384 * call;  // ds1 = +0, ds2 = +128, ds3 = +256
        call++;
        dim3 cgv(7, 16, BB);
        if (fused) {
            conv_mfma_kernel<48, 56, 64, 66, 8, true, false, false, true>
                <<<cgv, dim3(512), 0, stream>>>(
                zcur, (const s8v*)apk1, nullptr, y64, ds, nullptr, nullptr, nullptr,
                Fb, alpha, zcur, nX);
        } else {
            conv_mfma_kernel<48, 56, 64, 66, 8, true, false, false, false>
                <<<cgv, dim3(512), 0, stream>>>(
                zin, (const s8v*)apk1, nullptr, y64, ds, nullptr, nullptr, nullptr,
                nullptr, nullptr, nullptr, 0);
        }
        conv_mfma_kernel<64, 72, 48, 50, 6, false, true, true, false>
            <<<cgv, dim3(512), 0, stream>>>(
            y64, (const s8v*)apk2, h, Fdst, ds + 128, ds, g1, be1,
            nullptr, nullptr, nullptr, 0);
        const bf16_t* zread = fused ? zcur : zin;
        add_relu_gn2_kernel<<<dim3(100, BB), dim3(192), 0, stream>>>(
            Fdst, zread, ds + 128, g2, be2, ds + 256);
        gn3_gram_kernel<<<dim3(100, BB), dim3(192), 0, stream>>>(
            Fdst, zread, Fdst, Gdst, ds + 256, g3, be3, Gb, jslot, nf, gram);
    };

    // slot 0: X=0, F0=f(0), G0=F0 (gram[0,0] accumulated in gn3)
    resnet(zcur, Fb, Gb, 0, 1, false, 0);
    // slot 1: X=F0 -> zin IS Fb slot 0
    resnet(Fb, Fb + (size_t)SLOT, Gb + (size_t)SLOT, 1, 2, false, 0);

    for (int k = 2; k <= 24; k++) {
        int n = imin(k, 5);
        int j = k % 5;
        int nf = imin(k + 1, 5);
        solve_kernel<<<1, 64, 0, stream>>>(gram, alpha, n, j, nf);
        if (k < 24)   // conv1 of this resnet forms z_k = sum alpha_j F_j itself
            resnet(nullptr, Fb + (size_t)j * SLOT, Gb + (size_t)j * SLOT, j, nf, true, n);
    }

    // z_star from k=24's alpha; final f application into F slot 0 (no G, no gram)
    resnet(nullptr, Fb, nullptr, 0, 0, true, 5);

    // final linear: NHWC [8,128,200,48] x fw[10,200] -> out [8,48,128,10]
    fc_kernel<<<BB * HH, dim3(512), 0, stream>>>(Fb, fcw, fcb, out);
}

// Round 14
// 4550.724 us; speedup vs baseline: 1.0360x; 1.0197x over previous
//
#include <hip/hip_runtime.h>

#define BB   8
#define HH   128
#define WW   200
#define HWSZ 25600
#define C48  48
#define C64  64
#define NGRP 8
#define EPSV 1e-5f
#define LAMV 1e-4
#define SLOT 9830400          // BB*C48*HWSZ elements (one z/F/G slot)
#define DPB  1228800          // C48*HWSZ per-batch flat dim
#define Y64SZ 13107200        // BB*C64*HWSZ
#define BIGELEMS 131072000ull // 12*SLOT + Y64SZ

typedef unsigned short bf16_t;
typedef __attribute__((ext_vector_type(4))) short s4v;
typedef __attribute__((ext_vector_type(8))) short s8v;
typedef __attribute__((ext_vector_type(16))) float f32x16;

__device__ inline float b2f(bf16_t b) { return __uint_as_float(((unsigned)b) << 16); }
__device__ inline bf16_t f2b(float f) {
    unsigned u = __float_as_uint(f);
    unsigned r = u + 0x7fffu + ((u >> 16) & 1u);
    return (bf16_t)(r >> 16);
}
__device__ inline float lo16(unsigned u) { return __uint_as_float(u << 16); }
__device__ inline float hi16(unsigned u) { return __uint_as_float(u & 0xffff0000u); }
__device__ inline unsigned pack2(float lo, float hi) {
    return ((unsigned)f2b(lo)) | (((unsigned)f2b(hi)) << 16);
}
__device__ inline float4 ld4(const bf16_t* p) {
    ushort4 u = *(const ushort4*)p;
    return make_float4(b2f(u.x), b2f(u.y), b2f(u.z), b2f(u.w));
}
__device__ inline void st4(bf16_t* p, float4 v) {
    ushort4 u; u.x = f2b(v.x); u.y = f2b(v.y); u.z = f2b(v.z); u.w = f2b(v.w);
    *(ushort4*)p = u;
}
// 8 bf16 <-> 8 floats via one 16B op
__device__ inline void ld8(const bf16_t* p, float* v) {
    uint4 u = *(const uint4*)p;
    v[0] = lo16(u.x); v[1] = hi16(u.x); v[2] = lo16(u.y); v[3] = hi16(u.y);
    v[4] = lo16(u.z); v[5] = hi16(u.z); v[6] = lo16(u.w); v[7] = hi16(u.w);
}
__device__ inline void st8(bf16_t* p, const float* v) {
    uint4 u;
    u.x = pack2(v[0], v[1]); u.y = pack2(v[2], v[3]);
    u.z = pack2(v[4], v[5]); u.w = pack2(v[6], v[7]);
    *(uint4*)p = u;
}

// (mean, invstd) from f64 sums at use site
__device__ inline void ms_from(const double* __restrict__ ds, int pair, double invcnt,
                               float& mean, float& inv) {
    double s = ds[2 * pair], q = ds[2 * pair + 1];
    double m = s * invcnt;
    double v = q * invcnt - m * m;
    mean = (float)m;
    inv = (float)(1.0 / sqrt(v + (double)EPSV));
}

// ---------------- utility ----------------

__global__ void zero_kernel(float* __restrict__ p, int n) {
    int i = blockIdx.x * 256 + threadIdx.x;
    if (i < n) p[i] = 0.f;
}
__global__ void fill16_kernel(float4* __restrict__ p) {
    float4 z; z.x = z.y = z.z = z.w = 0.f;
    p[(size_t)blockIdx.x * 256 + threadIdx.x] = z;
}

// ---------------- weight packing: [kc][tap][mt][lane][8] bf16 ----------------
__global__ void pack_kernel(const float* __restrict__ w, bf16_t* __restrict__ apk,
                            int CIN, int CO_real, int total) {
    int idx = blockIdx.x * 256 + threadIdx.x;
    if (idx >= total) return;
    int j   = idx & 7;
    int l   = (idx >> 3) & 63;
    int mt  = (idx >> 9) & 1;
    int tap = (idx >> 10) % 9;
    int kc  = idx / 9216;
    int co = mt * 32 + (l & 31);
    int ci = kc * 16 + (l >> 5) * 8 + j;
    float v = (co < CO_real) ? w[((size_t)co * CIN + ci) * 9 + tap] : 0.f;
    apk[idx] = f2b(v);
}

// ---------------- conv0 (1->48) + fused BN stats (R9-proven) ----------------
__global__ __launch_bounds__(256) void conv0_kernel(
    const float* __restrict__ x, const float* __restrict__ w0,
    const float* __restrict__ b0, float* __restrict__ out,
    double* __restrict__ bnbin)
{
    __shared__ float xs[3 * 202];
    __shared__ float wt[480];
    __shared__ float ss[48], qq[48];
    const int tid = threadIdx.x;
    const int bI = blockIdx.x / HH, y = blockIdx.x % HH;
    for (int i = tid; i < 606; i += 256) {
        int r = i / 202, cc = i % 202;
        int gy = y + r - 1, gx = cc - 1;
        float v = 0.f;
        if ((unsigned)gy < (unsigned)HH && (unsigned)gx < (unsigned)WW)
            v = x[(size_t)bI * HWSZ + gy * WW + gx];
        xs[r * 202 + cc] = v;
    }
    for (int i = tid; i < 480; i += 256) wt[i] = (i < 432) ? w0[i] : b0[i - 432];
    if (tid < 48) { ss[tid] = 0.f; qq[tid] = 0.f; }
    __syncthreads();
    const size_t obase = (((size_t)bI * HH + y) * WW) * 48;
    float4 sacc[3], qacc[3];
    #pragma unroll
    for (int j = 0; j < 3; j++) {
        sacc[j] = make_float4(0.f, 0.f, 0.f, 0.f);
        qacc[j] = make_float4(0.f, 0.f, 0.f, 0.f);
    }
    int k3 = 0;
    for (int ch = tid; ch < 2400; ch += 256) {
        int px = (ch * 4) / 48, c0 = (ch * 4) % 48;
        float xv[3][3];
        #pragma unroll
        for (int r = 0; r < 3; r++)
            #pragma unroll
            for (int dx = 0; dx < 3; dx++)
                xv[r][dx] = xs[r * 202 + px + dx];
        float4 o;
        #pragma unroll
        for (int j = 0; j < 4; j++) {
            int c = c0 + j;
            float acc = wt[432 + c];
            #pragma unroll
            for (int r = 0; r < 3; r++)
                #pragma unroll
                for (int dx = 0; dx < 3; dx++)
                    acc = fmaf(xv[r][dx], wt[c * 9 + r * 3 + dx], acc);
            ((float*)&o)[j] = acc;
        }
        *(float4*)(out + obase + ch * 4) = o;
        sacc[k3].x += o.x; sacc[k3].y += o.y; sacc[k3].z += o.z; sacc[k3].w += o.w;
        qacc[k3].x = fmaf(o.x, o.x, qacc[k3].x);
        qacc[k3].y = fmaf(o.y, o.y, qacc[k3].y);
        qacc[k3].z = fmaf(o.z, o.z, qacc[k3].z);
        qacc[k3].w = fmaf(o.w, o.w, qacc[k3].w);
        k3 = (k3 == 2) ? 0 : k3 + 1;
    }
    #pragma unroll
    for (int j = 0; j < 3; j++) {
        int quad = (tid + 4 * j) % 12;
        atomicAdd(&ss[quad * 4 + 0], sacc[j].x);
        atomicAdd(&ss[quad * 4 + 1], sacc[j].y);
        atomicAdd(&ss[quad * 4 + 2], sacc[j].z);
        atomicAdd(&ss[quad * 4 + 3], sacc[j].w);
        atomicAdd(&qq[quad * 4 + 0], qacc[j].x);
        atomicAdd(&qq[quad * 4 + 1], qacc[j].y);
        atomicAdd(&qq[quad * 4 + 2], qacc[j].z);
        atomicAdd(&qq[quad * 4 + 3], qacc[j].w);
    }
    __syncthreads();
    if (tid < 48) {
        int bin = blockIdx.x & 7;
        unsafeAtomicAdd(&bnbin[bin * 96 + tid * 2],     (double)ss[tid]);
        unsafeAtomicAdd(&bnbin[bin * 96 + tid * 2 + 1], (double)qq[tid]);
    }
}

// 1-block: dstats[0..95] = sum of 8 bins
__global__ void bn_reduce_kernel(const double* __restrict__ bnbin, double* __restrict__ dst) {
    int t = threadIdx.x;
    if (t < 96) {
        double s = 0.0;
        #pragma unroll
        for (int j = 0; j < 8; j++) s += bnbin[j * 96 + t];
        dst[t] = s;
    }
}

// ---------------- BN apply: fp32 NHWC raw -> bf16 NHWC h ----------------
__global__ __launch_bounds__(256) void bn_apply_kernel(
    const float* __restrict__ src, bf16_t* __restrict__ dst,
    const float* __restrict__ gamma, const float* __restrict__ beta,
    const double* __restrict__ ds)
{
    __shared__ float gaT[48], beT[48];
    int tid = threadIdx.x;
    if (tid < 48) {
        float mean, inv; ms_from(ds, tid, 1.0 / 204800.0, mean, inv);
        float ga = gamma[tid] * inv;
        gaT[tid] = ga; beT[tid] = beta[tid] - mean * ga;
    }
    __syncthreads();
    size_t base = (size_t)blockIdx.x * 1024 + (size_t)tid * 4;
    int c0 = (int)(base % 48);
    float4 v = *(const float4*)(src + base);
    ushort4 o;
    o.x = f2b(fmaf(v.x, gaT[c0],     beT[c0]));
    o.y = f2b(fmaf(v.y, gaT[c0 + 1], beT[c0 + 1]));
    o.z = f2b(fmaf(v.z, gaT[c0 + 2], beT[c0 + 2]));
    o.w = f2b(fmaf(v.w, gaT[c0 + 3], beT[c0 + 3]));
    *(ushort4*)(dst + base) = o;
}

// ---------------- MFMA implicit-GEMM 3x3 conv (R5/R9 structure) ----------------
// R14 = R13 resubmitted verbatim (R13 bench was an infra failure, no data).
// FUSEXK staging gets the R5 batched-MLP treatment — R12's serial 5-dependent-
// load-per-item chain violated the batching lesson and ate the xk saving. XK5 variant
// (n==5, 20 of 23 calls): phase A issues ALL NIT x 5 slot loads into vr[] (80 VGPR),
// one wait, phase B combines/packs/stores. Dynamic-n variant keeps R12's serial path.
template<int CIN, int CIPAD, int CO, int OTS, int CG, bool RELU, bool ADDH, bool FOLDGN,
         bool FUSEXK, bool XK5>
__global__ __launch_bounds__(512, 4) void conv_mfma_kernel(
    const bf16_t* __restrict__ in, const s8v* __restrict__ apk,
    const bf16_t* __restrict__ hadd, bf16_t* __restrict__ out,
    double* __restrict__ dsOut,
    const double* __restrict__ dsPrev, const float* __restrict__ gPrev,
    const float* __restrict__ bPrev,
    const bf16_t* __restrict__ FbX, const float* __restrict__ alphaX,
    bf16_t* __restrict__ zwr, int nX)
{
    constexpr int KC  = CIN / 16;
    constexpr int NC8 = CIN / 8;
    constexpr int NITEMS = 10 * 34 * NC8;
    constexpr int NIT = (NITEMS + 511) / 512;
    const int tid  = threadIdx.x;
    const int lane = tid & 63;
    const int wv   = tid >> 6;          // 0..7 = output row within block
    const int x0 = blockIdx.x * 32;
    const int y0 = blockIdx.y * 8;
    const int b  = blockIdx.z;

    __shared__ __align__(16) bf16_t bt[10 * 34 * CIPAD];  // reused as ot[256][OTS]
    __shared__ __align__(16) s8v ws[1152];                // one kc-slice of apk (18.4KB)
    __shared__ __align__(16) float gaT[FOLDGN ? CIN : 4];
    __shared__ __align__(16) float beT[FOLDGN ? CIN : 4];
    __shared__ float ss[512], qq[512];

    if (FOLDGN) {
        if (tid < CIN) {
            float mean, inv;
            ms_from(dsPrev, b * NGRP + tid / (CIN / NGRP), 1.0 / 204800.0, mean, inv);
            float ga = gPrev[tid] * inv;
            gaT[tid] = ga; beT[tid] = bPrev[tid] - mean * ga;
        }
        __syncthreads();
    }

    if (FUSEXK && XK5) {
        // ---- fused xk, n==5, batched: all NIT*5 loads in flight, one wait ----
        float al[5];
        #pragma unroll
        for (int j = 0; j < 5; j++) al[j] = alphaX[b * 5 + j];
        const bf16_t* bb = FbX + (size_t)b * DPB;
        unsigned goff[NIT];
        s8v vr[NIT][5];
        #pragma unroll
        for (int k = 0; k < NIT; k++) {
            int i = tid + k * 512;
            unsigned go = 0xFFFFFFFFu;
            if (i < NITEMS) {
                int ch8 = i % NC8, p = i / NC8;
                int r = p / 34, c = p - r * 34;
                int gy = y0 + r - 1, gx = x0 + c - 1;
                if ((unsigned)gy < (unsigned)HH && (unsigned)gx < (unsigned)WW)
                    go = (unsigned)((gy * WW + gx) * CIN + ch8 * 8);
            }
            goff[k] = go;
            #pragma unroll
            for (int j = 0; j < 5; j++) {
                s8v t;
                #pragma unroll
                for (int e = 0; e < 8; e++) t[e] = 0;
                if (go != 0xFFFFFFFFu)
                    t = *(const s8v*)(bb + (size_t)j * SLOT + go);
                vr[k][j] = t;
            }
        }
        #pragma unroll
        for (int k = 0; k < NIT; k++) {
            int i = tid + k * 512;
            if (i >= NITEMS) continue;
            int ch8 = i % NC8, p = i / NC8;
            s8v v;
            #pragma unroll
            for (int e = 0; e < 8; e++) v[e] = 0;
            if (goff[k] != 0xFFFFFFFFu) {
                float zf[8] = {0.f, 0.f, 0.f, 0.f, 0.f, 0.f, 0.f, 0.f};
                #pragma unroll
                for (int j = 0; j < 5; j++) {
                    float f[8];
                    uint4 u = *(uint4*)&vr[k][j];
                    f[0] = lo16(u.x); f[1] = hi16(u.x); f[2] = lo16(u.y); f[3] = hi16(u.y);
                    f[4] = lo16(u.z); f[5] = hi16(u.z); f[6] = lo16(u.w); f[7] = hi16(u.w);
                    #pragma unroll
                    for (int e = 0; e < 8; e++) zf[e] = fmaf(f[e], al[j], zf[e]);
                }
                uint4 upk;
                upk.x = pack2(zf[0], zf[1]); upk.y = pack2(zf[2], zf[3]);
                upk.z = pack2(zf[4], zf[5]); upk.w = pack2(zf[6], zf[7]);
                v = *(s8v*)&upk;
                int r = p / 34, c = p - r * 34;
                if (r >= 1 && r <= 8 && c >= 1 && c <= 32)
                    *(s8v*)(zwr + (size_t)b * DPB + goff[k]) = v;  // interior once
            }
            *(s8v*)(bt + p * CIPAD + ch8 * 8) = v;
        }
    } else if (FUSEXK) {
        // ---- fused xk, dynamic n (3 calls: n=2..4) — R12-proven serial path ----
        float al[5];
        #pragma unroll
        for (int j = 0; j < 5; j++) al[j] = (j < nX) ? alphaX[b * 5 + j] : 0.f;
        for (int k = 0; k < NIT; k++) {
            int i = tid + k * 512;
            if (i >= NITEMS) continue;
            int ch8 = i % NC8, p = i / NC8;
            int r = p / 34, c = p - r * 34;
            int gy = y0 + r - 1, gx = x0 + c - 1;
            s8v v;
            #pragma unroll
            for (int e = 0; e < 8; e++) v[e] = 0;
            if ((unsigned)gy < (unsigned)HH && (unsigned)gx < (unsigned)WW) {
                size_t gidx = (((size_t)b * HH + gy) * WW + gx) * CIN + ch8 * 8;
                float zf[8] = {0.f, 0.f, 0.f, 0.f, 0.f, 0.f, 0.f, 0.f};
                #pragma unroll
                for (int j = 0; j < 5; j++) {
                    if (j < nX) {
                        float f[8];
                        ld8(FbX + (size_t)j * SLOT + gidx, f);
                        #pragma unroll
                        for (int e = 0; e < 8; e++) zf[e] = fmaf(f[e], al[j], zf[e]);
                    }
                }
                uint4 upk;
                upk.x = pack2(zf[0], zf[1]); upk.y = pack2(zf[2], zf[3]);
                upk.z = pack2(zf[4], zf[5]); upk.w = pack2(zf[6], zf[7]);
                v = *(s8v*)&upk;
                if (r >= 1 && r <= 8 && c >= 1 && c <= 32)
                    *(s8v*)(zwr + gidx) = v;    // interior: each 16B written once
            }
            *(s8v*)(bt + p * CIPAD + ch8 * 8) = v;
        }
    } else {
        // ---- input staging, batched: issue all loads, single wait, then fold+write ----
        s8v vreg[NIT];
        #pragma unroll
        for (int k = 0; k < NIT; k++) {
            int i = tid + k * 512;
            s8v t;
            #pragma unroll
            for (int e = 0; e < 8; e++) t[e] = 0;
            if (i < NITEMS) {
                int ch8 = i % NC8, p = i / NC8;
                int r = p / 34, c = p - r * 34;
                int gy = y0 + r - 1, gx = x0 + c - 1;
                if ((unsigned)gy < (unsigned)HH && (unsigned)gx < (unsigned)WW)
                    t = *(const s8v*)(in + ((((size_t)b * HH + gy) * WW + gx) * CIN + ch8 * 8));
            }
            vreg[k] = t;
        }
        #pragma unroll
        for (int k = 0; k < NIT; k++) {
            int i = tid + k * 512;
            if (i >= NITEMS) continue;
            int ch8 = i % NC8, p = i / NC8;
            s8v v = vreg[k];
            if (FOLDGN) {
                int r = p / 34, c = p - r * 34;
                int gy = y0 + r - 1, gx = x0 + c - 1;
                if ((unsigned)gy < (unsigned)HH && (unsigned)gx < (unsigned)WW) {
                    const float* ga8 = &gaT[ch8 * 8];
                    const float* be8 = &beT[ch8 * 8];
                    float f[8];
                    #pragma unroll
                    for (int e = 0; e < 8; e++)
                        f[e] = fmaf(b2f((bf16_t)(unsigned short)v[e]), ga8[e], be8[e]);
                    unsigned p01, p23, p45, p67;
                    asm("v_cvt_pk_bf16_f32 %0, %1, %2" : "=v"(p01) : "v"(f[0]), "v"(f[1]));
                    asm("v_cvt_pk_bf16_f32 %0, %1, %2" : "=v"(p23) : "v"(f[2]), "v"(f[3]));
                    asm("v_cvt_pk_bf16_f32 %0, %1, %2" : "=v"(p45) : "v"(f[4]), "v"(f[5]));
                    asm("v_cvt_pk_bf16_f32 %0, %1, %2" : "=v"(p67) : "v"(f[6]), "v"(f[7]));
                    unsigned* vp = (unsigned*)&v;
                    vp[0] = p01; vp[1] = p23; vp[2] = p45; vp[3] = p67;
                }
            }
            *(s8v*)(bt + p * CIPAD + ch8 * 8) = v;
        }
    }

    const int n = lane & 31, half = lane >> 5;
    f32x16 acc0, acc1;
    #pragma unroll
    for (int i = 0; i < 16; i++) { acc0[i] = 0.f; acc1[i] = 0.f; }

    // ---- kc-outer: stage weight slice to LDS, then 9 taps of MFMA ----
    #pragma unroll
    for (int kc = 0; kc < KC; kc++) {
        if (kc) __syncthreads();               // previous ws readers done
        for (int i = tid; i < 1152; i += 512)
            ws[i] = apk[(size_t)kc * 1152 + i];
        __syncthreads();                       // ws ready (kc=0: also bt ready)
        #pragma unroll
        for (int ky = 0; ky < 3; ky++)
        #pragma unroll
        for (int kx = 0; kx < 3; kx++) {
            const int tap = ky * 3 + kx;
            s8v a0 = ws[tap * 128 + lane];
            s8v a1 = ws[tap * 128 + 64 + lane];
            const bf16_t* brow = bt + ((wv + ky) * 34 + n + kx) * CIPAD + half * 8;
            s8v bfrag = *(const s8v*)(brow + kc * 16);
            acc0 = __builtin_amdgcn_mfma_f32_32x32x16_bf16(a0, bfrag, acc0, 0, 0, 0);
            acc1 = __builtin_amdgcn_mfma_f32_32x32x16_bf16(a1, bfrag, acc1, 0, 0, 0);
        }
    }
    __syncthreads();   // bt/ws reads done; reuse bt as ot

    bf16_t* ot = bt;
    {
        const int pxl = wv * 32 + n;   // 0..255
        const bool pv = (x0 + n) < WW;
        #pragma unroll
        for (int g4 = 0; g4 < 4; g4++) {
            s4v pk0;
            #pragma unroll
            for (int jj = 0; jj < 4; jj++) {
                float v = acc0[g4 * 4 + jj];
                if (RELU) v = fmaxf(v, 0.f);
                pk0[jj] = (short)(pv ? f2b(v) : (bf16_t)0);
            }
            *(s4v*)&ot[pxl * OTS + g4 * 8 + 4 * half] = pk0;
            const int c1b = 32 + g4 * 8 + 4 * half;
            if (c1b + 3 < CO) {
                s4v pk1;
                #pragma unroll
                for (int jj = 0; jj < 4; jj++) {
                    float v = acc1[g4 * 4 + jj];
                    if (RELU) v = fmaxf(v, 0.f);
                    pk1[jj] = (short)(pv ? f2b(v) : (bf16_t)0);
                }
                *(s4v*)&ot[pxl * OTS + c1b] = pk1;
            }
        }
    }
    __syncthreads();
    {
        constexpr int NCH8 = 256 * CO / 8;
        for (int ch = tid; ch < NCH8; ch += 512) {
            int pxl = ch / (CO / 8);
            int co0 = (ch % (CO / 8)) * 8;
            int row = pxl >> 5, col = pxl & 31;
            int xx = x0 + col;
            if (xx < WW) {
                bf16_t* lp = &ot[pxl * OTS + co0];
                size_t ga = (((size_t)b * HH + y0 + row) * WW + xx) * CO + co0;
                if (ADDH) {
                    float4 h0 = ld4(hadd + ga), h1 = ld4(hadd + ga + 4);
                    float4 l0 = ld4(lp), l1 = ld4(lp + 4);
                    float4 v0 = make_float4(l0.x + h0.x, l0.y + h0.y, l0.z + h0.z, l0.w + h0.w);
                    float4 v1 = make_float4(l1.x + h1.x, l1.y + h1.y, l1.z + h1.z, l1.w + h1.w);
                    st4(out + ga, v0); st4(out + ga + 4, v1);
                    st4(lp, v0); st4(lp + 4, v1);
                } else {
                    *(ushort4*)(out + ga)     = *(ushort4*)lp;
                    *(ushort4*)(out + ga + 4) = *(ushort4*)(lp + 4);
                }
            }
        }
    }
    if (ADDH) __syncthreads();
    {
        constexpr int NPH = 512 / CO;
        const int c = tid % CO, rr = tid / CO;
        float s = 0.f, q = 0.f;
        if (rr < NPH) {
            for (int px = rr; px < 256; px += NPH) {
                float v = b2f(ot[px * OTS + c]);
                s += v; q += v * v;
            }
        }
        ss[tid] = s; qq[tid] = q;
        __syncthreads();
        if (tid < CO) {
            float S = ss[tid], Q = qq[tid];
            #pragma unroll
            for (int p = 1; p < NPH; p++) { S += ss[tid + p * CO]; Q += qq[tid + p * CO]; }
            ss[tid] = S; qq[tid] = Q;
        }
        __syncthreads();
        if (tid < NGRP) {
            float S = 0.f, Q = 0.f;
            #pragma unroll
            for (int j = 0; j < CG; j++) { S += ss[tid * CG + j]; Q += qq[tid * CG + j]; }
            unsafeAtomicAdd(&dsOut[((size_t)b * NGRP + tid) * 2],     (double)S);
            unsafeAtomicAdd(&dsOut[((size_t)b * NGRP + tid) * 2 + 1], (double)Q);
        }
    }
}

// ---------------- v = relu(z + gn2(u)) in place on u, looped + register group stats ----------
// (100,B) x 8 iters — R8 proved (200,B) regresses (same-address f64 atomic serialization).
__global__ __launch_bounds__(192) void add_relu_gn2_kernel(
    bf16_t* __restrict__ u, const bf16_t* __restrict__ z,
    const double* __restrict__ ds2, const float* __restrict__ g2,
    const float* __restrict__ b2, double* __restrict__ ds3)
{
    __shared__ float sm[16];
    const int tid = threadIdx.x;
    const int c0 = 8 * (tid % 6), pxr = tid / 6;
    const int b = blockIdx.y;
    if (tid < 16) sm[tid] = 0.f;
    const int gA = c0 / 6;
    const int split = (gA + 1) * 6 - c0;
    float meanA, invA, meanB, invB;
    ms_from(ds2, b * NGRP + gA,     1.0 / 153600.0, meanA, invA);
    ms_from(ds2, b * NGRP + gA + 1, 1.0 / 153600.0, meanB, invB);
    float wga[8], wbe[8];
    #pragma unroll
    for (int e = 0; e < 8; e++) {
        int c = c0 + e;
        float m = (e < split) ? meanA : meanB, iv = (e < split) ? invA : invB;
        float ga = g2[c] * iv;
        wga[e] = ga; wbe[e] = b2[c] - m * ga;
    }
    __syncthreads();
    const size_t pxbase = (size_t)b * HWSZ + (size_t)blockIdx.x * 256;
    float sA = 0.f, qA = 0.f, sB = 0.f, qB = 0.f;
    for (int it = 0; it < 8; it++) {
        size_t idx = (pxbase + it * 32 + pxr) * 48 + c0;
        float uu[8], zz[8], vv[8];
        ld8(u + idx, uu); ld8(z + idx, zz);
        #pragma unroll
        for (int e = 0; e < 8; e++) {
            float v = fmaxf(fmaf(uu[e], wga[e], wbe[e]) + zz[e], 0.f);
            vv[e] = v;
            if (e < split) { sA += v; qA += v * v; } else { sB += v; qB += v * v; }
        }
        st8(u + idx, vv);
    }
    atomicAdd(&sm[2 * gA], sA);     atomicAdd(&sm[2 * gA + 1], qA);
    atomicAdd(&sm[2 * gA + 2], sB); atomicAdd(&sm[2 * gA + 3], qB);
    __syncthreads();
    if (tid < NGRP) {
        unsafeAtomicAdd(&ds3[(b * NGRP + tid) * 2],     (double)sm[tid * 2]);
        unsafeAtomicAdd(&ds3[(b * NGRP + tid) * 2 + 1], (double)sm[tid * 2 + 1]);
    }
}

// ---------------- gn3 apply + fused Gram row, looped (MLP) ----------------
// (100,B) x 8 iters. Solve stays separate (R7 VGPR-poisoning lesson).
__global__ __launch_bounds__(192) void gn3_gram_kernel(
    const bf16_t* __restrict__ v, const bf16_t* __restrict__ z,
    bf16_t* __restrict__ F, bf16_t* __restrict__ G,
    const double* __restrict__ ds3, const float* __restrict__ g3,
    const float* __restrict__ b3,
    const bf16_t* __restrict__ Gall, int jslot, int nf, double* __restrict__ gram)
{
    __shared__ double red[3][5];
    const int tid = threadIdx.x;
    const int c0 = 8 * (tid % 6), pxr = tid / 6;
    const int b = blockIdx.y;
    const int gA = c0 / 6;
    const int split = (gA + 1) * 6 - c0;
    float meanA, invA, meanB, invB;
    ms_from(ds3, b * NGRP + gA,     1.0 / 153600.0, meanA, invA);
    ms_from(ds3, b * NGRP + gA + 1, 1.0 / 153600.0, meanB, invB);
    float wga[8], wbe[8];
    #pragma unroll
    for (int e = 0; e < 8; e++) {
        int c = c0 + e;
        float m = (e < split) ? meanA : meanB, iv = (e < split) ? invA : invB;
        float ga = g3[c] * iv;
        wga[e] = ga; wbe[e] = b3[c] - m * ga;
    }
    const size_t pxbase = (size_t)b * HWSZ + (size_t)blockIdx.x * 256;
    double dot[5] = {0.0, 0.0, 0.0, 0.0, 0.0};
    for (int it = 0; it < 8; it++) {
        size_t idx = (pxbase + it * 32 + pxr) * 48 + c0;
        float rr[8];
        ld8(v + idx, rr);
        #pragma unroll
        for (int e = 0; e < 8; e++) rr[e] = fmaf(rr[e], wga[e], wbe[e]);
        st8(F + idx, rr);
        if (nf > 0) {
            float zz[8], gg[8];
            ld8(z + idx, zz);
            #pragma unroll
            for (int e = 0; e < 8; e++) gg[e] = rr[e] - zz[e];
            st8(G + idx, gg);
            #pragma unroll
            for (int i = 0; i < 5; i++) {
                if (i >= nf) continue;
                float d = 0.f;
                if (i == jslot) {
                    #pragma unroll
                    for (int e = 0; e < 8; e++) d = fmaf(gg[e], gg[e], d);
                } else {
                    float gi[8];
                    ld8(Gall + (size_t)i * SLOT + idx, gi);
                    #pragma unroll
                    for (int e = 0; e < 8; e++) d = fmaf(gg[e], gi[e], d);
                }
                dot[i] += (double)d;
            }
        }
    }
    if (nf > 0) {
        #pragma unroll
        for (int i = 0; i < 5; i++) {
            if (i >= nf) continue;
            #pragma unroll
            for (int off = 32; off > 0; off >>= 1) dot[i] += __shfl_down(dot[i], off);
        }
        int wv = tid >> 6;
        if ((tid & 63) == 0) {
            #pragma unroll
            for (int i = 0; i < 5; i++) if (i < nf) red[wv][i] = dot[i];
        }
        __syncthreads();
        if (tid == 0) {
            #pragma unroll
            for (int i = 0; i < 5; i++) {
                if (i >= nf) continue;
                double D = red[0][i] + red[1][i] + red[2][i];
                unsafeAtomicAdd(&gram[b * 25 + jslot * 5 + i], D);
                if (i != jslot) unsafeAtomicAdd(&gram[b * 25 + i * 5 + jslot], D);
            }
        }
    }
}

// ---------------- Anderson solve + gram row/col zeroing ----------------
// Each thread b reads its gram block into registers FIRST, then zeroes its own
// row/col jz — per-thread ordering suffices (no cross-thread gram use).
__global__ void solve_kernel(double* __restrict__ gram, float* __restrict__ alpha,
                             int n, int jz, int nf) {
    int b = threadIdx.x;
    if (b >= BB) return;
    const int m = n + 1;
    double A[6][7];
    for (int i = 0; i < m; i++)
        for (int jj = 0; jj <= m; jj++) A[i][jj] = 0.0;
    for (int i = 1; i < m; i++) { A[0][i] = 1.0; A[i][0] = 1.0; }
    for (int i = 1; i < m; i++)
        for (int jj = 1; jj < m; jj++)
            A[i][jj] = gram[b * 25 + (i - 1) * 5 + (jj - 1)] + ((i == jj) ? LAMV : 0.0);
    A[0][m] = 1.0;
    for (int col = 0; col < m; col++) {
        int piv = col; double best = fabs(A[col][col]);
        for (int rr = col + 1; rr < m; rr++) {
            double tv = fabs(A[rr][col]);
            if (tv > best) { best = tv; piv = rr; }
        }
        if (piv != col)
            for (int cc = col; cc <= m; cc++) {
                double tmp = A[col][cc]; A[col][cc] = A[piv][cc]; A[piv][cc] = tmp;
            }
        double invp = 1.0 / A[col][col];
        for (int cc = col; cc <= m; cc++) A[col][cc] *= invp;
        for (int rr = 0; rr < m; rr++) {
            if (rr == col) continue;
            double f = A[rr][col];
            if (f != 0.0)
                for (int cc = col; cc <= m; cc++) A[rr][cc] = fma(-f, A[col][cc], A[rr][cc]);
        }
    }
    for (int i = 0; i < n; i++) alpha[b * 5 + i] = (float)A[i + 1][m];
    for (int i = 0; i < nf; i++) {
        gram[b * 25 + jz * 5 + i] = 0.0;
        gram[b * 25 + i * 5 + jz] = 0.0;
    }
}

// ---------------- final linear (NHWC bf16 in) ----------------
__global__ __launch_bounds__(512) void fc_kernel(
    const bf16_t* __restrict__ zf, const float* __restrict__ fw,
    const float* __restrict__ fb, float* __restrict__ out)
{
    __shared__ bf16_t row[9600];
    __shared__ float fwT[2000];
    int tid = threadIdx.x;
    int b = blockIdx.x >> 7, hh = blockIdx.x & 127;
    size_t base = (((size_t)b * HH + hh) * WW) * 48;
    for (int i = tid; i < 2400; i += 512)
        *(ushort4*)&row[i * 4] = *(const ushort4*)(zf + base + (size_t)i * 4);
    for (int i = tid; i < 2000; i += 512) fwT[i] = fw[i];
    __syncthreads();
    if (tid < 480) {
        int c = tid % 48, o = tid / 48;
        float acc = fb[o];
        #pragma unroll 4
        for (int w = 0; w < 200; w++)
            acc = fmaf(b2f(row[w * 48 + c]), fwT[o * 200 + w], acc);
        out[(((size_t)b * 48 + c) * HH + hh) * 10 + o] = acc;
    }
}

// ---------------- host ----------------

static inline int imin(int a, int b) { return a < b ? a : b; }

extern "C" void kernel_launch(void* const* d_in, const int* in_sizes, int n_in,
                              void* d_out, int out_size, void* d_ws, size_t ws_size,
                              hipStream_t stream)
{
    const float* x   = (const float*)d_in[0];
    const float* w0  = (const float*)d_in[1];
    const float* b0  = (const float*)d_in[2];
    const float* bng = (const float*)d_in[3];
    const float* bnb = (const float*)d_in[4];
    const float* w1  = (const float*)d_in[5];
    const float* w2  = (const float*)d_in[6];
    const float* g1  = (const float*)d_in[7];
    const float* be1 = (const float*)d_in[8];
    const float* g2  = (const float*)d_in[9];
    const float* be2 = (const float*)d_in[10];
    const float* g3  = (const float*)d_in[11];
    const float* be3 = (const float*)d_in[12];
    const float* fcw = (const float*)d_in[13];
    const float* fcb = (const float*)d_in[14];
    float* out = (float*)d_out;

    bf16_t* h    = (bf16_t*)d_ws;           // SLOT    (NHWC)
    bf16_t* zcur = h + (size_t)SLOT;        // SLOT
    bf16_t* y64  = zcur + (size_t)SLOT;     // Y64SZ
    bf16_t* Fb   = y64 + (size_t)Y64SZ;     // 5*SLOT
    bf16_t* Gb   = Fb + 5 * (size_t)SLOT;   // 5*SLOT
    double* dstats = (double*)((char*)d_ws + BIGELEMS * 2);  // 9696 dbl: BN 96 + 25*384
    double* gram   = dstats + 9696;                          // 200 dbl
    float*  alpha  = (float*)(gram + 200);                   // 40 f
    double* bnbin  = (double*)(alpha + 40);                  // 768 dbl (8 bins x 96)
    bf16_t* apk1   = (bf16_t*)(bnbin + 768);                 // 27648
    bf16_t* apk2   = apk1 + 27648;                           // 36864
    float*  scratch = (float*)Gb;  // conv0 raw fp32 (G region dead at that point)

    const size_t need = BIGELEMS * 2 + 9696 * 8 + 200 * 8 + 40 * 4 + 768 * 8
                        + (27648 + 36864) * 2;
    if (ws_size < need) return;

    const dim3 blk(256);
    const int CHUNKS16 = SLOT * 2 / 16 / 256;  // 4800

    // zero dstats + gram + alpha + bnbin = 9696*2 + 200*2 + 40 + 768*2 = 21368 floats
    zero_kernel<<<(21368 + 255) / 256, blk, 0, stream>>>((float*)dstats, 21368);
    pack_kernel<<<108, blk, 0, stream>>>(w1, apk1, 48, 64, 27648);
    pack_kernel<<<144, blk, 0, stream>>>(w2, apk2, 64, 48, 36864);
    fill16_kernel<<<CHUNKS16, blk, 0, stream>>>((float4*)zcur);

    // h = BN(conv0(x)+b0) in NHWC bf16; stats fused into conv0, 8-way binned
    conv0_kernel<<<BB * HH, blk, 0, stream>>>(x, w0, b0, scratch, bnbin);
    bn_reduce_kernel<<<1, 128, 0, stream>>>(bnbin, dstats);
    bn_apply_kernel<<<SLOT / 1024, blk, 0, stream>>>(scratch, h, bng, bnb, dstats);

    int call = 0;
    // fused=0: zin staged directly. fused=1: dynamic n. fused=2: n==5 batched variant.
    auto resnet = [&](const bf16_t* zin, bf16_t* Fdst, bf16_t* Gdst, int jslot, int nf,
                      int fused, int nX) {
        double* ds = dstats + 96 + 384 * call;  // ds1 = +0, ds2 = +128, ds3 = +256
        call++;
        dim3 cgv(7, 16, BB);
        if (fused == 2) {
            conv_mfma_kernel<48, 56, 64, 66, 8, true, false, false, true, true>
                <<<cgv, dim3(512), 0, stream>>>(
                zcur, (const s8v*)apk1, nullptr, y64, ds, nullptr, nullptr, nullptr,
                Fb, alpha, zcur, 5);
        } else if (fused == 1) {
            conv_mfma_kernel<48, 56, 64, 66, 8, true, false, false, true, false>
                <<<cgv, dim3(512), 0, stream>>>(
                zcur, (const s8v*)apk1, nullptr, y64, ds, nullptr, nullptr, nullptr,
                Fb, alpha, zcur, nX);
        } else {
            conv_mfma_kernel<48, 56, 64, 66, 8, true, false, false, false, false>
                <<<cgv, dim3(512), 0, stream>>>(
                zin, (const s8v*)apk1, nullptr, y64, ds, nullptr, nullptr, nullptr,
                nullptr, nullptr, nullptr, 0);
        }
        conv_mfma_kernel<64, 72, 48, 50, 6, false, true, true, false, false>
            <<<cgv, dim3(512), 0, stream>>>(
            y64, (const s8v*)apk2, h, Fdst, ds + 128, ds, g1, be1,
            nullptr, nullptr, nullptr, 0);
        const bf16_t* zread = fused ? zcur : zin;
        add_relu_gn2_kernel<<<dim3(100, BB), dim3(192), 0, stream>>>(
            Fdst, zread, ds + 128, g2, be2, ds + 256);
        gn3_gram_kernel<<<dim3(100, BB), dim3(192), 0, stream>>>(
            Fdst, zread, Fdst, Gdst, ds + 256, g3, be3, Gb, jslot, nf, gram);
    };

    // slot 0: X=0, F0=f(0), G0=F0 (gram[0,0] accumulated in gn3)
    resnet(zcur, Fb, Gb, 0, 1, 0, 0);
    // slot 1: X=F0 -> zin IS Fb slot 0
    resnet(Fb, Fb + (size_t)SLOT, Gb + (size_t)SLOT, 1, 2, 0, 0);

    for (int k = 2; k <= 24; k++) {
        int n = imin(k, 5);
        int j = k % 5;
        int nf = imin(k + 1, 5);
        solve_kernel<<<1, 64, 0, stream>>>(gram, alpha, n, j, nf);
        if (k < 24)   // conv1 of this resnet forms z_k = sum alpha_j F_j itself
            resnet(nullptr, Fb + (size_t)j * SLOT, Gb + (size_t)j * SLOT, j, nf,
                   (n == 5) ? 2 : 1, n);
    }

    // z_star from k=24's alpha; final f application into F slot 0 (no G, no gram)
    resnet(nullptr, Fb, nullptr, 0, 0, 2, 5);

    // final linear: NHWC [8,128,200,48] x fw[10,200] -> out [8,48,128,10]
    fc_kernel<<<BB * HH, dim3(512), 0, stream>>>(Fb, fcw, fcb, out);
}

// Round 15
// 4343.648 us; speedup vs baseline: 1.0853x; 1.0477x over previous
//
#include <hip/hip_runtime.h>

#define BB   8
#define HH   128
#define WW   200
#define HWSZ 25600
#define C48  48
#define C64  64
#define NGRP 8
#define EPSV 1e-5f
#define LAMV 1e-4
#define SLOT 9830400          // BB*C48*HWSZ elements (one z/F/G slot)
#define DPB  1228800          // C48*HWSZ per-batch flat dim
#define Y64SZ 13107200        // BB*C64*HWSZ
#define BIGELEMS 131072000ull // 12*SLOT + Y64SZ

typedef unsigned short bf16_t;
typedef __attribute__((ext_vector_type(4))) short s4v;
typedef __attribute__((ext_vector_type(8))) short s8v;
typedef __attribute__((ext_vector_type(16))) float f32x16;

__device__ inline float b2f(bf16_t b) { return __uint_as_float(((unsigned)b) << 16); }
__device__ inline bf16_t f2b(float f) {
    unsigned u = __float_as_uint(f);
    unsigned r = u + 0x7fffu + ((u >> 16) & 1u);
    return (bf16_t)(r >> 16);
}
__device__ inline float lo16(unsigned u) { return __uint_as_float(u << 16); }
__device__ inline float hi16(unsigned u) { return __uint_as_float(u & 0xffff0000u); }
__device__ inline unsigned pack2(float lo, float hi) {
    return ((unsigned)f2b(lo)) | (((unsigned)f2b(hi)) << 16);
}
__device__ inline float4 ld4(const bf16_t* p) {
    ushort4 u = *(const ushort4*)p;
    return make_float4(b2f(u.x), b2f(u.y), b2f(u.z), b2f(u.w));
}
__device__ inline void st4(bf16_t* p, float4 v) {
    ushort4 u; u.x = f2b(v.x); u.y = f2b(v.y); u.z = f2b(v.z); u.w = f2b(v.w);
    *(ushort4*)p = u;
}
// 8 bf16 <-> 8 floats via one 16B op
__device__ inline void ld8(const bf16_t* p, float* v) {
    uint4 u = *(const uint4*)p;
    v[0] = lo16(u.x); v[1] = hi16(u.x); v[2] = lo16(u.y); v[3] = hi16(u.y);
    v[4] = lo16(u.z); v[5] = hi16(u.z); v[6] = lo16(u.w); v[7] = hi16(u.w);
}
__device__ inline void st8(bf16_t* p, const float* v) {
    uint4 u;
    u.x = pack2(v[0], v[1]); u.y = pack2(v[2], v[3]);
    u.z = pack2(v[4], v[5]); u.w = pack2(v[6], v[7]);
    *(uint4*)p = u;
}

// (mean, invstd) from f64 sums at use site
__device__ inline void ms_from(const double* __restrict__ ds, int pair, double invcnt,
                               float& mean, float& inv) {
    double s = ds[2 * pair], q = ds[2 * pair + 1];
    double m = s * invcnt;
    double v = q * invcnt - m * m;
    mean = (float)m;
    inv = (float)(1.0 / sqrt(v + (double)EPSV));
}

// ---------------- utility ----------------

__global__ void zero_kernel(float* __restrict__ p, int n) {
    int i = blockIdx.x * 256 + threadIdx.x;
    if (i < n) p[i] = 0.f;
}
__global__ void fill16_kernel(float4* __restrict__ p) {
    float4 z; z.x = z.y = z.z = z.w = 0.f;
    p[(size_t)blockIdx.x * 256 + threadIdx.x] = z;
}

// ---------------- weight packing: [kc][tap][mt][lane][8] bf16 ----------------
__global__ void pack_kernel(const float* __restrict__ w, bf16_t* __restrict__ apk,
                            int CIN, int CO_real, int total) {
    int idx = blockIdx.x * 256 + threadIdx.x;
    if (idx >= total) return;
    int j   = idx & 7;
    int l   = (idx >> 3) & 63;
    int mt  = (idx >> 9) & 1;
    int tap = (idx >> 10) % 9;
    int kc  = idx / 9216;
    int co = mt * 32 + (l & 31);
    int ci = kc * 16 + (l >> 5) * 8 + j;
    float v = (co < CO_real) ? w[((size_t)co * CIN + ci) * 9 + tap] : 0.f;
    apk[idx] = f2b(v);
}

// ---------------- conv0 (1->48) + fused BN stats (R9-proven) ----------------
__global__ __launch_bounds__(256) void conv0_kernel(
    const float* __restrict__ x, const float* __restrict__ w0,
    const float* __restrict__ b0, float* __restrict__ out,
    double* __restrict__ bnbin)
{
    __shared__ float xs[3 * 202];
    __shared__ float wt[480];
    __shared__ float ss[48], qq[48];
    const int tid = threadIdx.x;
    const int bI = blockIdx.x / HH, y = blockIdx.x % HH;
    for (int i = tid; i < 606; i += 256) {
        int r = i / 202, cc = i % 202;
        int gy = y + r - 1, gx = cc - 1;
        float v = 0.f;
        if ((unsigned)gy < (unsigned)HH && (unsigned)gx < (unsigned)WW)
            v = x[(size_t)bI * HWSZ + gy * WW + gx];
        xs[r * 202 + cc] = v;
    }
    for (int i = tid; i < 480; i += 256) wt[i] = (i < 432) ? w0[i] : b0[i - 432];
    if (tid < 48) { ss[tid] = 0.f; qq[tid] = 0.f; }
    __syncthreads();
    const size_t obase = (((size_t)bI * HH + y) * WW) * 48;
    float4 sacc[3], qacc[3];
    #pragma unroll
    for (int j = 0; j < 3; j++) {
        sacc[j] = make_float4(0.f, 0.f, 0.f, 0.f);
        qacc[j] = make_float4(0.f, 0.f, 0.f, 0.f);
    }
    int k3 = 0;
    for (int ch = tid; ch < 2400; ch += 256) {
        int px = (ch * 4) / 48, c0 = (ch * 4) % 48;
        float xv[3][3];
        #pragma unroll
        for (int r = 0; r < 3; r++)
            #pragma unroll
            for (int dx = 0; dx < 3; dx++)
                xv[r][dx] = xs[r * 202 + px + dx];
        float4 o;
        #pragma unroll
        for (int j = 0; j < 4; j++) {
            int c = c0 + j;
            float acc = wt[432 + c];
            #pragma unroll
            for (int r = 0; r < 3; r++)
                #pragma unroll
                for (int dx = 0; dx < 3; dx++)
                    acc = fmaf(xv[r][dx], wt[c * 9 + r * 3 + dx], acc);
            ((float*)&o)[j] = acc;
        }
        *(float4*)(out + obase + ch * 4) = o;
        sacc[k3].x += o.x; sacc[k3].y += o.y; sacc[k3].z += o.z; sacc[k3].w += o.w;
        qacc[k3].x = fmaf(o.x, o.x, qacc[k3].x);
        qacc[k3].y = fmaf(o.y, o.y, qacc[k3].y);
        qacc[k3].z = fmaf(o.z, o.z, qacc[k3].z);
        qacc[k3].w = fmaf(o.w, o.w, qacc[k3].w);
        k3 = (k3 == 2) ? 0 : k3 + 1;
    }
    #pragma unroll
    for (int j = 0; j < 3; j++) {
        int quad = (tid + 4 * j) % 12;
        atomicAdd(&ss[quad * 4 + 0], sacc[j].x);
        atomicAdd(&ss[quad * 4 + 1], sacc[j].y);
        atomicAdd(&ss[quad * 4 + 2], sacc[j].z);
        atomicAdd(&ss[quad * 4 + 3], sacc[j].w);
        atomicAdd(&qq[quad * 4 + 0], qacc[j].x);
        atomicAdd(&qq[quad * 4 + 1], qacc[j].y);
        atomicAdd(&qq[quad * 4 + 2], qacc[j].z);
        atomicAdd(&qq[quad * 4 + 3], qacc[j].w);
    }
    __syncthreads();
    if (tid < 48) {
        int bin = blockIdx.x & 7;
        unsafeAtomicAdd(&bnbin[bin * 96 + tid * 2],     (double)ss[tid]);
        unsafeAtomicAdd(&bnbin[bin * 96 + tid * 2 + 1], (double)qq[tid]);
    }
}

// 1-block: dstats[0..95] = sum of 8 bins
__global__ void bn_reduce_kernel(const double* __restrict__ bnbin, double* __restrict__ dst) {
    int t = threadIdx.x;
    if (t < 96) {
        double s = 0.0;
        #pragma unroll
        for (int j = 0; j < 8; j++) s += bnbin[j * 96 + t];
        dst[t] = s;
    }
}

// ---------------- BN apply: fp32 NHWC raw -> bf16 NHWC h ----------------
__global__ __launch_bounds__(256) void bn_apply_kernel(
    const float* __restrict__ src, bf16_t* __restrict__ dst,
    const float* __restrict__ gamma, const float* __restrict__ beta,
    const double* __restrict__ ds)
{
    __shared__ float gaT[48], beT[48];
    int tid = threadIdx.x;
    if (tid < 48) {
        float mean, inv; ms_from(ds, tid, 1.0 / 204800.0, mean, inv);
        float ga = gamma[tid] * inv;
        gaT[tid] = ga; beT[tid] = beta[tid] - mean * ga;
    }
    __syncthreads();
    size_t base = (size_t)blockIdx.x * 1024 + (size_t)tid * 4;
    int c0 = (int)(base % 48);
    float4 v = *(const float4*)(src + base);
    ushort4 o;
    o.x = f2b(fmaf(v.x, gaT[c0],     beT[c0]));
    o.y = f2b(fmaf(v.y, gaT[c0 + 1], beT[c0 + 1]));
    o.z = f2b(fmaf(v.z, gaT[c0 + 2], beT[c0 + 2]));
    o.w = f2b(fmaf(v.w, gaT[c0 + 3], beT[c0 + 3]));
    *(ushort4*)(dst + base) = o;
}

// ---------------- MFMA implicit-GEMM 3x3 conv (R14-proven, incl. batched XK5) ----------
template<int CIN, int CIPAD, int CO, int OTS, int CG, bool RELU, bool ADDH, bool FOLDGN,
         bool FUSEXK, bool XK5>
__global__ __launch_bounds__(512, 4) void conv_mfma_kernel(
    const bf16_t* __restrict__ in, const s8v* __restrict__ apk,
    const bf16_t* __restrict__ hadd, bf16_t* __restrict__ out,
    double* __restrict__ dsOut,
    const double* __restrict__ dsPrev, const float* __restrict__ gPrev,
    const float* __restrict__ bPrev,
    const bf16_t* __restrict__ FbX, const float* __restrict__ alphaX,
    bf16_t* __restrict__ zwr, int nX)
{
    constexpr int KC  = CIN / 16;
    constexpr int NC8 = CIN / 8;
    constexpr int NITEMS = 10 * 34 * NC8;
    constexpr int NIT = (NITEMS + 511) / 512;
    const int tid  = threadIdx.x;
    const int lane = tid & 63;
    const int wv   = tid >> 6;          // 0..7 = output row within block
    const int x0 = blockIdx.x * 32;
    const int y0 = blockIdx.y * 8;
    const int b  = blockIdx.z;

    __shared__ __align__(16) bf16_t bt[10 * 34 * CIPAD];  // reused as ot[256][OTS]
    __shared__ __align__(16) s8v ws[1152];                // one kc-slice of apk (18.4KB)
    __shared__ __align__(16) float gaT[FOLDGN ? CIN : 4];
    __shared__ __align__(16) float beT[FOLDGN ? CIN : 4];
    __shared__ float ss[512], qq[512];

    if (FOLDGN) {
        if (tid < CIN) {
            float mean, inv;
            ms_from(dsPrev, b * NGRP + tid / (CIN / NGRP), 1.0 / 204800.0, mean, inv);
            float ga = gPrev[tid] * inv;
            gaT[tid] = ga; beT[tid] = bPrev[tid] - mean * ga;
        }
        __syncthreads();
    }

    if (FUSEXK && XK5) {
        // ---- fused xk, n==5, batched: all NIT*5 loads in flight, one wait ----
        float al[5];
        #pragma unroll
        for (int j = 0; j < 5; j++) al[j] = alphaX[b * 5 + j];
        const bf16_t* bb = FbX + (size_t)b * DPB;
        unsigned goff[NIT];
        s8v vr[NIT][5];
        #pragma unroll
        for (int k = 0; k < NIT; k++) {
            int i = tid + k * 512;
            unsigned go = 0xFFFFFFFFu;
            if (i < NITEMS) {
                int ch8 = i % NC8, p = i / NC8;
                int r = p / 34, c = p - r * 34;
                int gy = y0 + r - 1, gx = x0 + c - 1;
                if ((unsigned)gy < (unsigned)HH && (unsigned)gx < (unsigned)WW)
                    go = (unsigned)((gy * WW + gx) * CIN + ch8 * 8);
            }
            goff[k] = go;
            #pragma unroll
            for (int j = 0; j < 5; j++) {
                s8v t;
                #pragma unroll
                for (int e = 0; e < 8; e++) t[e] = 0;
                if (go != 0xFFFFFFFFu)
                    t = *(const s8v*)(bb + (size_t)j * SLOT + go);
                vr[k][j] = t;
            }
        }
        #pragma unroll
        for (int k = 0; k < NIT; k++) {
            int i = tid + k * 512;
            if (i >= NITEMS) continue;
            int ch8 = i % NC8, p = i / NC8;
            s8v v;
            #pragma unroll
            for (int e = 0; e < 8; e++) v[e] = 0;
            if (goff[k] != 0xFFFFFFFFu) {
                float zf[8] = {0.f, 0.f, 0.f, 0.f, 0.f, 0.f, 0.f, 0.f};
                #pragma unroll
                for (int j = 0; j < 5; j++) {
                    float f[8];
                    uint4 u = *(uint4*)&vr[k][j];
                    f[0] = lo16(u.x); f[1] = hi16(u.x); f[2] = lo16(u.y); f[3] = hi16(u.y);
                    f[4] = lo16(u.z); f[5] = hi16(u.z); f[6] = lo16(u.w); f[7] = hi16(u.w);
                    #pragma unroll
                    for (int e = 0; e < 8; e++) zf[e] = fmaf(f[e], al[j], zf[e]);
                }
                uint4 upk;
                upk.x = pack2(zf[0], zf[1]); upk.y = pack2(zf[2], zf[3]);
                upk.z = pack2(zf[4], zf[5]); upk.w = pack2(zf[6], zf[7]);
                v = *(s8v*)&upk;
                int r = p / 34, c = p - r * 34;
                if (r >= 1 && r <= 8 && c >= 1 && c <= 32)
                    *(s8v*)(zwr + (size_t)b * DPB + goff[k]) = v;  // interior once
            }
            *(s8v*)(bt + p * CIPAD + ch8 * 8) = v;
        }
    } else if (FUSEXK) {
        // ---- fused xk, dynamic n (3 calls: n=2..4) — R12-proven serial path ----
        float al[5];
        #pragma unroll
        for (int j = 0; j < 5; j++) al[j] = (j < nX) ? alphaX[b * 5 + j] : 0.f;
        for (int k = 0; k < NIT; k++) {
            int i = tid + k * 512;
            if (i >= NITEMS) continue;
            int ch8 = i % NC8, p = i / NC8;
            int r = p / 34, c = p - r * 34;
            int gy = y0 + r - 1, gx = x0 + c - 1;
            s8v v;
            #pragma unroll
            for (int e = 0; e < 8; e++) v[e] = 0;
            if ((unsigned)gy < (unsigned)HH && (unsigned)gx < (unsigned)WW) {
                size_t gidx = (((size_t)b * HH + gy) * WW + gx) * CIN + ch8 * 8;
                float zf[8] = {0.f, 0.f, 0.f, 0.f, 0.f, 0.f, 0.f, 0.f};
                #pragma unroll
                for (int j = 0; j < 5; j++) {
                    if (j < nX) {
                        float f[8];
                        ld8(FbX + (size_t)j * SLOT + gidx, f);
                        #pragma unroll
                        for (int e = 0; e < 8; e++) zf[e] = fmaf(f[e], al[j], zf[e]);
                    }
                }
                uint4 upk;
                upk.x = pack2(zf[0], zf[1]); upk.y = pack2(zf[2], zf[3]);
                upk.z = pack2(zf[4], zf[5]); upk.w = pack2(zf[6], zf[7]);
                v = *(s8v*)&upk;
                if (r >= 1 && r <= 8 && c >= 1 && c <= 32)
                    *(s8v*)(zwr + gidx) = v;    // interior: each 16B written once
            }
            *(s8v*)(bt + p * CIPAD + ch8 * 8) = v;
        }
    } else {
        // ---- input staging, batched: issue all loads, single wait, then fold+write ----
        s8v vreg[NIT];
        #pragma unroll
        for (int k = 0; k < NIT; k++) {
            int i = tid + k * 512;
            s8v t;
            #pragma unroll
            for (int e = 0; e < 8; e++) t[e] = 0;
            if (i < NITEMS) {
                int ch8 = i % NC8, p = i / NC8;
                int r = p / 34, c = p - r * 34;
                int gy = y0 + r - 1, gx = x0 + c - 1;
                if ((unsigned)gy < (unsigned)HH && (unsigned)gx < (unsigned)WW)
                    t = *(const s8v*)(in + ((((size_t)b * HH + gy) * WW + gx) * CIN + ch8 * 8));
            }
            vreg[k] = t;
        }
        #pragma unroll
        for (int k = 0; k < NIT; k++) {
            int i = tid + k * 512;
            if (i >= NITEMS) continue;
            int ch8 = i % NC8, p = i / NC8;
            s8v v = vreg[k];
            if (FOLDGN) {
                int r = p / 34, c = p - r * 34;
                int gy = y0 + r - 1, gx = x0 + c - 1;
                if ((unsigned)gy < (unsigned)HH && (unsigned)gx < (unsigned)WW) {
                    const float* ga8 = &gaT[ch8 * 8];
                    const float* be8 = &beT[ch8 * 8];
                    float f[8];
                    #pragma unroll
                    for (int e = 0; e < 8; e++)
                        f[e] = fmaf(b2f((bf16_t)(unsigned short)v[e]), ga8[e], be8[e]);
                    unsigned p01, p23, p45, p67;
                    asm("v_cvt_pk_bf16_f32 %0, %1, %2" : "=v"(p01) : "v"(f[0]), "v"(f[1]));
                    asm("v_cvt_pk_bf16_f32 %0, %1, %2" : "=v"(p23) : "v"(f[2]), "v"(f[3]));
                    asm("v_cvt_pk_bf16_f32 %0, %1, %2" : "=v"(p45) : "v"(f[4]), "v"(f[5]));
                    asm("v_cvt_pk_bf16_f32 %0, %1, %2" : "=v"(p67) : "v"(f[6]), "v"(f[7]));
                    unsigned* vp = (unsigned*)&v;
                    vp[0] = p01; vp[1] = p23; vp[2] = p45; vp[3] = p67;
                }
            }
            *(s8v*)(bt + p * CIPAD + ch8 * 8) = v;
        }
    }

    const int n = lane & 31, half = lane >> 5;
    f32x16 acc0, acc1;
    #pragma unroll
    for (int i = 0; i < 16; i++) { acc0[i] = 0.f; acc1[i] = 0.f; }

    // ---- kc-outer: stage weight slice to LDS, then 9 taps of MFMA ----
    #pragma unroll
    for (int kc = 0; kc < KC; kc++) {
        if (kc) __syncthreads();               // previous ws readers done
        for (int i = tid; i < 1152; i += 512)
            ws[i] = apk[(size_t)kc * 1152 + i];
        __syncthreads();                       // ws ready (kc=0: also bt ready)
        #pragma unroll
        for (int ky = 0; ky < 3; ky++)
        #pragma unroll
        for (int kx = 0; kx < 3; kx++) {
            const int tap = ky * 3 + kx;
            s8v a0 = ws[tap * 128 + lane];
            s8v a1 = ws[tap * 128 + 64 + lane];
            const bf16_t* brow = bt + ((wv + ky) * 34 + n + kx) * CIPAD + half * 8;
            s8v bfrag = *(const s8v*)(brow + kc * 16);
            acc0 = __builtin_amdgcn_mfma_f32_32x32x16_bf16(a0, bfrag, acc0, 0, 0, 0);
            acc1 = __builtin_amdgcn_mfma_f32_32x32x16_bf16(a1, bfrag, acc1, 0, 0, 0);
        }
    }
    __syncthreads();   // bt/ws reads done; reuse bt as ot

    bf16_t* ot = bt;
    {
        const int pxl = wv * 32 + n;   // 0..255
        const bool pv = (x0 + n) < WW;
        #pragma unroll
        for (int g4 = 0; g4 < 4; g4++) {
            s4v pk0;
            #pragma unroll
            for (int jj = 0; jj < 4; jj++) {
                float v = acc0[g4 * 4 + jj];
                if (RELU) v = fmaxf(v, 0.f);
                pk0[jj] = (short)(pv ? f2b(v) : (bf16_t)0);
            }
            *(s4v*)&ot[pxl * OTS + g4 * 8 + 4 * half] = pk0;
            const int c1b = 32 + g4 * 8 + 4 * half;
            if (c1b + 3 < CO) {
                s4v pk1;
                #pragma unroll
                for (int jj = 0; jj < 4; jj++) {
                    float v = acc1[g4 * 4 + jj];
                    if (RELU) v = fmaxf(v, 0.f);
                    pk1[jj] = (short)(pv ? f2b(v) : (bf16_t)0);
                }
                *(s4v*)&ot[pxl * OTS + c1b] = pk1;
            }
        }
    }
    __syncthreads();
    {
        constexpr int NCH8 = 256 * CO / 8;
        for (int ch = tid; ch < NCH8; ch += 512) {
            int pxl = ch / (CO / 8);
            int co0 = (ch % (CO / 8)) * 8;
            int row = pxl >> 5, col = pxl & 31;
            int xx = x0 + col;
            if (xx < WW) {
                bf16_t* lp = &ot[pxl * OTS + co0];
                size_t ga = (((size_t)b * HH + y0 + row) * WW + xx) * CO + co0;
                if (ADDH) {
                    float4 h0 = ld4(hadd + ga), h1 = ld4(hadd + ga + 4);
                    float4 l0 = ld4(lp), l1 = ld4(lp + 4);
                    float4 v0 = make_float4(l0.x + h0.x, l0.y + h0.y, l0.z + h0.z, l0.w + h0.w);
                    float4 v1 = make_float4(l1.x + h1.x, l1.y + h1.y, l1.z + h1.z, l1.w + h1.w);
                    st4(out + ga, v0); st4(out + ga + 4, v1);
                    st4(lp, v0); st4(lp + 4, v1);
                } else {
                    *(ushort4*)(out + ga)     = *(ushort4*)lp;
                    *(ushort4*)(out + ga + 4) = *(ushort4*)(lp + 4);
                }
            }
        }
    }
    if (ADDH) __syncthreads();
    {
        constexpr int NPH = 512 / CO;
        const int c = tid % CO, rr = tid / CO;
        float s = 0.f, q = 0.f;
        if (rr < NPH) {
            for (int px = rr; px < 256; px += NPH) {
                float v = b2f(ot[px * OTS + c]);
                s += v; q += v * v;
            }
        }
        ss[tid] = s; qq[tid] = q;
        __syncthreads();
        if (tid < CO) {
            float S = ss[tid], Q = qq[tid];
            #pragma unroll
            for (int p = 1; p < NPH; p++) { S += ss[tid + p * CO]; Q += qq[tid + p * CO]; }
            ss[tid] = S; qq[tid] = Q;
        }
        __syncthreads();
        if (tid < NGRP) {
            float S = 0.f, Q = 0.f;
            #pragma unroll
            for (int j = 0; j < CG; j++) { S += ss[tid * CG + j]; Q += qq[tid * CG + j]; }
            unsafeAtomicAdd(&dsOut[((size_t)b * NGRP + tid) * 2],     (double)S);
            unsafeAtomicAdd(&dsOut[((size_t)b * NGRP + tid) * 2 + 1], (double)Q);
        }
    }
}

// ---------------- gn2 STATS-ONLY: reads u,z; accumulates ds3; writes NOTHING ----------
// R15: v write (19.7MB/iter) eliminated — gn3 recomputes v from u,z. Grid (50,B) x 384
// (was (100,B) x 192): R8 measured +14.5µs/call per +100 blocks (per-block fixed cost +
// same-address f64 atomic serialization); halving block count reverses that slope.
__global__ __launch_bounds__(384) void gn2_stats_kernel(
    const bf16_t* __restrict__ u, const bf16_t* __restrict__ z,
    const double* __restrict__ ds2, const float* __restrict__ g2,
    const float* __restrict__ b2, double* __restrict__ ds3)
{
    __shared__ float sm[16];
    const int tid = threadIdx.x;
    const int c0 = 8 * (tid % 6), pxr = tid / 6;   // pxr 0..63
    const int b = blockIdx.y;
    if (tid < 16) sm[tid] = 0.f;
    const int gA = c0 / 6;
    const int split = (gA + 1) * 6 - c0;
    float meanA, invA, meanB, invB;
    ms_from(ds2, b * NGRP + gA,     1.0 / 153600.0, meanA, invA);
    ms_from(ds2, b * NGRP + gA + 1, 1.0 / 153600.0, meanB, invB);
    float wga[8], wbe[8];
    #pragma unroll
    for (int e = 0; e < 8; e++) {
        int c = c0 + e;
        float m = (e < split) ? meanA : meanB, iv = (e < split) ? invA : invB;
        float ga = g2[c] * iv;
        wga[e] = ga; wbe[e] = b2[c] - m * ga;
    }
    __syncthreads();
    const size_t pxbase = (size_t)b * HWSZ + (size_t)blockIdx.x * 512;
    float sA = 0.f, qA = 0.f, sB = 0.f, qB = 0.f;
    for (int it = 0; it < 8; it++) {
        size_t idx = (pxbase + it * 64 + pxr) * 48 + c0;
        float uu[8], zz[8];
        ld8(u + idx, uu); ld8(z + idx, zz);
        #pragma unroll
        for (int e = 0; e < 8; e++) {
            float v = fmaxf(fmaf(uu[e], wga[e], wbe[e]) + zz[e], 0.f);
            if (e < split) { sA += v; qA += v * v; } else { sB += v; qB += v * v; }
        }
    }
    atomicAdd(&sm[2 * gA], sA);     atomicAdd(&sm[2 * gA + 1], qA);
    atomicAdd(&sm[2 * gA + 2], sB); atomicAdd(&sm[2 * gA + 3], qB);
    __syncthreads();
    if (tid < NGRP) {
        unsafeAtomicAdd(&ds3[(b * NGRP + tid) * 2],     (double)sm[tid * 2]);
        unsafeAtomicAdd(&ds3[(b * NGRP + tid) * 2 + 1], (double)sm[tid * 2 + 1]);
    }
}

// ---------------- gn3: recompute v from u,z (ds2), apply gn3, Gram row ----------------
// R15: v recomputed in f32 (consistent with ds3 stats, which were always pre-round);
// reads u instead of v — same bytes, but gn2's v write is gone. Grid (50,B) x 384.
__global__ __launch_bounds__(384) void gn3_gram_kernel(
    const bf16_t* __restrict__ u, const bf16_t* __restrict__ z,
    bf16_t* __restrict__ F, bf16_t* __restrict__ G,
    const double* __restrict__ ds2, const float* __restrict__ g2,
    const float* __restrict__ b2,
    const double* __restrict__ ds3, const float* __restrict__ g3,
    const float* __restrict__ b3,
    const bf16_t* __restrict__ Gall, int jslot, int nf, double* __restrict__ gram)
{
    __shared__ double red[6][5];
    const int tid = threadIdx.x;
    const int c0 = 8 * (tid % 6), pxr = tid / 6;   // pxr 0..63
    const int b = blockIdx.y;
    const int gA = c0 / 6;
    const int split = (gA + 1) * 6 - c0;
    float m2A, i2A, m2B, i2B, m3A, i3A, m3B, i3B;
    ms_from(ds2, b * NGRP + gA,     1.0 / 153600.0, m2A, i2A);
    ms_from(ds2, b * NGRP + gA + 1, 1.0 / 153600.0, m2B, i2B);
    ms_from(ds3, b * NGRP + gA,     1.0 / 153600.0, m3A, i3A);
    ms_from(ds3, b * NGRP + gA + 1, 1.0 / 153600.0, m3B, i3B);
    float wga2[8], wbe2[8], wga3[8], wbe3[8];
    #pragma unroll
    for (int e = 0; e < 8; e++) {
        int c = c0 + e;
        float m2 = (e < split) ? m2A : m2B, i2 = (e < split) ? i2A : i2B;
        float ga2 = g2[c] * i2;
        wga2[e] = ga2; wbe2[e] = b2[c] - m2 * ga2;
        float m3 = (e < split) ? m3A : m3B, i3 = (e < split) ? i3A : i3B;
        float ga3 = g3[c] * i3;
        wga3[e] = ga3; wbe3[e] = b3[c] - m3 * ga3;
    }
    const size_t pxbase = (size_t)b * HWSZ + (size_t)blockIdx.x * 512;
    double dot[5] = {0.0, 0.0, 0.0, 0.0, 0.0};
    for (int it = 0; it < 8; it++) {
        size_t idx = (pxbase + it * 64 + pxr) * 48 + c0;
        float uu[8], zz[8], rr[8];
        ld8(u + idx, uu); ld8(z + idx, zz);
        #pragma unroll
        for (int e = 0; e < 8; e++) {
            float v = fmaxf(fmaf(uu[e], wga2[e], wbe2[e]) + zz[e], 0.f);
            rr[e] = fmaf(v, wga3[e], wbe3[e]);
        }
        st8(F + idx, rr);
        if (nf > 0) {
            float gg[8];
            #pragma unroll
            for (int e = 0; e < 8; e++) gg[e] = rr[e] - zz[e];
            st8(G + idx, gg);
            #pragma unroll
            for (int i = 0; i < 5; i++) {
                if (i >= nf) continue;
                float d = 0.f;
                if (i == jslot) {
                    #pragma unroll
                    for (int e = 0; e < 8; e++) d = fmaf(gg[e], gg[e], d);
                } else {
                    float gi[8];
                    ld8(Gall + (size_t)i * SLOT + idx, gi);
                    #pragma unroll
                    for (int e = 0; e < 8; e++) d = fmaf(gg[e], gi[e], d);
                }
                dot[i] += (double)d;
            }
        }
    }
    if (nf > 0) {
        #pragma unroll
        for (int i = 0; i < 5; i++) {
            if (i >= nf) continue;
            #pragma unroll
            for (int off = 32; off > 0; off >>= 1) dot[i] += __shfl_down(dot[i], off);
        }
        int wv = tid >> 6;   // 0..5
        if ((tid & 63) == 0) {
            #pragma unroll
            for (int i = 0; i < 5; i++) if (i < nf) red[wv][i] = dot[i];
        }
        __syncthreads();
        if (tid == 0) {
            #pragma unroll
            for (int i = 0; i < 5; i++) {
                if (i >= nf) continue;
                double D = red[0][i] + red[1][i] + red[2][i]
                         + red[3][i] + red[4][i] + red[5][i];
                unsafeAtomicAdd(&gram[b * 25 + jslot * 5 + i], D);
                if (i != jslot) unsafeAtomicAdd(&gram[b * 25 + i * 5 + jslot], D);
            }
        }
    }
}

// ---------------- Anderson solve + gram row/col zeroing ----------------
__global__ void solve_kernel(double* __restrict__ gram, float* __restrict__ alpha,
                             int n, int jz, int nf) {
    int b = threadIdx.x;
    if (b >= BB) return;
    const int m = n + 1;
    double A[6][7];
    for (int i = 0; i < m; i++)
        for (int jj = 0; jj <= m; jj++) A[i][jj] = 0.0;
    for (int i = 1; i < m; i++) { A[0][i] = 1.0; A[i][0] = 1.0; }
    for (int i = 1; i < m; i++)
        for (int jj = 1; jj < m; jj++)
            A[i][jj] = gram[b * 25 + (i - 1) * 5 + (jj - 1)] + ((i == jj) ? LAMV : 0.0);
    A[0][m] = 1.0;
    for (int col = 0; col < m; col++) {
        int piv = col; double best = fabs(A[col][col]);
        for (int rr = col + 1; rr < m; rr++) {
            double tv = fabs(A[rr][col]);
            if (tv > best) { best = tv; piv = rr; }
        }
        if (piv != col)
            for (int cc = col; cc <= m; cc++) {
                double tmp = A[col][cc]; A[col][cc] = A[piv][cc]; A[piv][cc] = tmp;
            }
        double invp = 1.0 / A[col][col];
        for (int cc = col; cc <= m; cc++) A[col][cc] *= invp;
        for (int rr = 0; rr < m; rr++) {
            if (rr == col) continue;
            double f = A[rr][col];
            if (f != 0.0)
                for (int cc = col; cc <= m; cc++) A[rr][cc] = fma(-f, A[col][cc], A[rr][cc]);
        }
    }
    for (int i = 0; i < n; i++) alpha[b * 5 + i] = (float)A[i + 1][m];
    for (int i = 0; i < nf; i++) {
        gram[b * 25 + jz * 5 + i] = 0.0;
        gram[b * 25 + i * 5 + jz] = 0.0;
    }
}

// ---------------- final linear (NHWC bf16 in) ----------------
__global__ __launch_bounds__(512) void fc_kernel(
    const bf16_t* __restrict__ zf, const float* __restrict__ fw,
    const float* __restrict__ fb, float* __restrict__ out)
{
    __shared__ bf16_t row[9600];
    __shared__ float fwT[2000];
    int tid = threadIdx.x;
    int b = blockIdx.x >> 7, hh = blockIdx.x & 127;
    size_t base = (((size_t)b * HH + hh) * WW) * 48;
    for (int i = tid; i < 2400; i += 512)
        *(ushort4*)&row[i * 4] = *(const ushort4*)(zf + base + (size_t)i * 4);
    for (int i = tid; i < 2000; i += 512) fwT[i] = fw[i];
    __syncthreads();
    if (tid < 480) {
        int c = tid % 48, o = tid / 48;
        float acc = fb[o];
        #pragma unroll 4
        for (int w = 0; w < 200; w++)
            acc = fmaf(b2f(row[w * 48 + c]), fwT[o * 200 + w], acc);
        out[(((size_t)b * 48 + c) * HH + hh) * 10 + o] = acc;
    }
}

// ---------------- host ----------------

static inline int imin(int a, int b) { return a < b ? a : b; }

extern "C" void kernel_launch(void* const* d_in, const int* in_sizes, int n_in,
                              void* d_out, int out_size, void* d_ws, size_t ws_size,
                              hipStream_t stream)
{
    const float* x   = (const float*)d_in[0];
    const float* w0  = (const float*)d_in[1];
    const float* b0  = (const float*)d_in[2];
    const float* bng = (const float*)d_in[3];
    const float* bnb = (const float*)d_in[4];
    const float* w1  = (const float*)d_in[5];
    const float* w2  = (const float*)d_in[6];
    const float* g1  = (const float*)d_in[7];
    const float* be1 = (const float*)d_in[8];
    const float* g2  = (const float*)d_in[9];
    const float* be2 = (const float*)d_in[10];
    const float* g3  = (const float*)d_in[11];
    const float* be3 = (const float*)d_in[12];
    const float* fcw = (const float*)d_in[13];
    const float* fcb = (const float*)d_in[14];
    float* out = (float*)d_out;

    bf16_t* h    = (bf16_t*)d_ws;           // SLOT    (NHWC)
    bf16_t* zcur = h + (size_t)SLOT;        // SLOT
    bf16_t* y64  = zcur + (size_t)SLOT;     // Y64SZ
    bf16_t* Fb   = y64 + (size_t)Y64SZ;     // 5*SLOT
    bf16_t* Gb   = Fb + 5 * (size_t)SLOT;   // 5*SLOT
    double* dstats = (double*)((char*)d_ws + BIGELEMS * 2);  // 9696 dbl: BN 96 + 25*384
    double* gram   = dstats + 9696;                          // 200 dbl
    float*  alpha  = (float*)(gram + 200);                   // 40 f
    double* bnbin  = (double*)(alpha + 40);                  // 768 dbl (8 bins x 96)
    bf16_t* apk1   = (bf16_t*)(bnbin + 768);                 // 27648
    bf16_t* apk2   = apk1 + 27648;                           // 36864
    float*  scratch = (float*)Gb;  // conv0 raw fp32 (G region dead at that point)

    const size_t need = BIGELEMS * 2 + 9696 * 8 + 200 * 8 + 40 * 4 + 768 * 8
                        + (27648 + 36864) * 2;
    if (ws_size < need) return;

    const dim3 blk(256);
    const int CHUNKS16 = SLOT * 2 / 16 / 256;  // 4800

    // zero dstats + gram + alpha + bnbin = 9696*2 + 200*2 + 40 + 768*2 = 21368 floats
    zero_kernel<<<(21368 + 255) / 256, blk, 0, stream>>>((float*)dstats, 21368);
    pack_kernel<<<108, blk, 0, stream>>>(w1, apk1, 48, 64, 27648);
    pack_kernel<<<144, blk, 0, stream>>>(w2, apk2, 64, 48, 36864);
    fill16_kernel<<<CHUNKS16, blk, 0, stream>>>((float4*)zcur);

    // h = BN(conv0(x)+b0) in NHWC bf16; stats fused into conv0, 8-way binned
    conv0_kernel<<<BB * HH, blk, 0, stream>>>(x, w0, b0, scratch, bnbin);
    bn_reduce_kernel<<<1, 128, 0, stream>>>(bnbin, dstats);
    bn_apply_kernel<<<SLOT / 1024, blk, 0, stream>>>(scratch, h, bng, bnb, dstats);

    int call = 0;
    // fused=0: zin staged directly. fused=1: dynamic n. fused=2: n==5 batched variant.
    auto resnet = [&](const bf16_t* zin, bf16_t* Fdst, bf16_t* Gdst, int jslot, int nf,
                      int fused, int nX) {
        double* ds = dstats + 96 + 384 * call;  // ds1 = +0, ds2 = +128, ds3 = +256
        call++;
        dim3 cgv(7, 16, BB);
        if (fused == 2) {
            conv_mfma_kernel<48, 56, 64, 66, 8, true, false, false, true, true>
                <<<cgv, dim3(512), 0, stream>>>(
                zcur, (const s8v*)apk1, nullptr, y64, ds, nullptr, nullptr, nullptr,
                Fb, alpha, zcur, 5);
        } else if (fused == 1) {
            conv_mfma_kernel<48, 56, 64, 66, 8, true, false, false, true, false>
                <<<cgv, dim3(512), 0, stream>>>(
                zcur, (const s8v*)apk1, nullptr, y64, ds, nullptr, nullptr, nullptr,
                Fb, alpha, zcur, nX);
        } else {
            conv_mfma_kernel<48, 56, 64, 66, 8, true, false, false, false, false>
                <<<cgv, dim3(512), 0, stream>>>(
                zin, (const s8v*)apk1, nullptr, y64, ds, nullptr, nullptr, nullptr,
                nullptr, nullptr, nullptr, 0);
        }
        conv_mfma_kernel<64, 72, 48, 50, 6, false, true, true, false, false>
            <<<cgv, dim3(512), 0, stream>>>(
            y64, (const s8v*)apk2, h, Fdst, ds + 128, ds, g1, be1,
            nullptr, nullptr, nullptr, 0);
        const bf16_t* zread = fused ? zcur : zin;
        gn2_stats_kernel<<<dim3(50, BB), dim3(384), 0, stream>>>(
            Fdst, zread, ds + 128, g2, be2, ds + 256);
        gn3_gram_kernel<<<dim3(50, BB), dim3(384), 0, stream>>>(
            Fdst, zread, Fdst, Gdst, ds + 128, g2, be2, ds + 256, g3, be3,
            Gb, jslot, nf, gram);
    };

    // slot 0: X=0, F0=f(0), G0=F0 (gram[0,0] accumulated in gn3)
    resnet(zcur, Fb, Gb, 0, 1, 0, 0);
    // slot 1: X=F0 -> zin IS Fb slot 0
    resnet(Fb, Fb + (size_t)SLOT, Gb + (size_t)SLOT, 1, 2, 0, 0);

    for (int k = 2; k <= 24; k++) {
        int n = imin(k, 5);
        int j = k % 5;
        int nf = imin(k + 1, 5);
        solve_kernel<<<1, 64, 0, stream>>>(gram, alpha, n, j, nf);
        if (k < 24)   // conv1 of this resnet forms z_k = sum alpha_j F_j itself
            resnet(nullptr, Fb + (size_t)j * SLOT, Gb + (size_t)j * SLOT, j, nf,
                   (n == 5) ? 2 : 1, n);
    }

    // z_star from k=24's alpha; final f application into F slot 0 (no G, no gram)
    resnet(nullptr, Fb, nullptr, 0, 0, 2, 5);

    // final linear: NHWC [8,128,200,48] x fw[10,200] -> out [8,48,128,10]
    fc_kernel<<<BB * HH, dim3(512), 0, stream>>>(Fb, fcw, fcb, out);
}